// Round 3
// baseline (312.702 us; speedup 1.0000x reference)
//
#include <hip/hip_runtime.h>

#define B_  32
#define LC_ 2048
#define LQ_ 256
#define D_  256
#define NEGH (-30000.0f)   // f16-safe mask value
#define MASKF (-100000.0f) // folded-mask bias: guarantees clamp to NEGH

typedef _Float16 f16;
typedef _Float16 f16x4 __attribute__((ext_vector_type(4)));
typedef _Float16 f16x8 __attribute__((ext_vector_type(8)));
typedef float    f32x4 __attribute__((ext_vector_type(4)));

// ---- K1: cast ctx->f16, qry->qry*wm f16; scm = ctx.wc (mask-folded), sqm ----
__global__ __launch_bounds__(256) void k_prep(
    const float* __restrict__ ctx, const float* __restrict__ qry,
    const float* __restrict__ w0,
    const int* __restrict__ cmask, const int* __restrict__ qmask,
    f16* __restrict__ ctx16, f16* __restrict__ qrywm16,
    float* __restrict__ scm, float* __restrict__ sqm)
{
    const int lane = threadIdx.x & 63;
    const int wave = threadIdx.x >> 6;
    const int row  = blockIdx.x * 4 + wave;
    const int NC = B_ * LC_;
    if (row < NC) {
        float4 v = *(const float4*)(ctx + (long long)row * D_ + lane * 4);
        f16x4 h; h[0] = (f16)v.x; h[1] = (f16)v.y; h[2] = (f16)v.z; h[3] = (f16)v.w;
        *(f16x4*)(ctx16 + (long long)row * D_ + lane * 4) = h;
        float4 wc = *(const float4*)(w0 + lane * 4);
        float s = v.x*wc.x + v.y*wc.y + v.z*wc.z + v.w*wc.w;
        #pragma unroll
        for (int off = 32; off > 0; off >>= 1) s += __shfl_down(s, off, 64);
        if (lane == 0) scm[row] = cmask[row] ? MASKF : s;
    } else {
        int r = row - NC;
        float4 v = *(const float4*)(qry + (long long)r * D_ + lane * 4);
        float4 wm = *(const float4*)(w0 + 2 * D_ + lane * 4);
        f16x4 h;
        h[0] = (f16)(v.x * wm.x); h[1] = (f16)(v.y * wm.y);
        h[2] = (f16)(v.z * wm.z); h[3] = (f16)(v.w * wm.w);
        *(f16x4*)(qrywm16 + (long long)r * D_ + lane * 4) = h;
        float4 wq = *(const float4*)(w0 + D_ + lane * 4);
        float s = v.x*wq.x + v.y*wq.y + v.z*wq.z + v.w*wq.w;
        #pragma unroll
        for (int off = 32; off > 0; off >>= 1) s += __shfl_down(s, off, 64);
        if (lane == 0) sqm[r] = qmask[r] ? MASKF : s;
    }
}

// ---- K2: transpose qry fp32 [q][d] -> f16 Bcat[0:256] rows [d][q] ----
__global__ __launch_bounds__(256) void k_tq(
    const float* __restrict__ in, f16* __restrict__ out)
{
    __shared__ float tile[64 * 65];
    const int b = blockIdx.z;
    const int r0 = blockIdx.x * 64, c0 = blockIdx.y * 64;
    const int t = threadIdx.x;
    const float* ib = in + (long long)b * LQ_ * D_;
    #pragma unroll
    for (int p = 0; p < 4; ++p) {
        int r = (t >> 4) + p * 16;
        int cb = (t & 15) * 4;
        float4 v = *(const float4*)(ib + (long long)(r0 + r) * D_ + c0 + cb);
        tile[r * 65 + cb + 0] = v.x;
        tile[r * 65 + cb + 1] = v.y;
        tile[r * 65 + cb + 2] = v.z;
        tile[r * 65 + cb + 3] = v.w;
    }
    __syncthreads();
    f16* ob = out + (long long)b * 512 * LQ_;
    #pragma unroll
    for (int p = 0; p < 4; ++p) {
        int c = (t >> 4) + p * 16;
        int rb = (t & 15) * 4;
        f16x4 h;
        h[0] = (f16)tile[(rb + 0) * 65 + c];
        h[1] = (f16)tile[(rb + 1) * 65 + c];
        h[2] = (f16)tile[(rb + 2) * 65 + c];
        h[3] = (f16)tile[(rb + 3) * 65 + c];
        *(f16x4*)(ob + (long long)(c0 + c) * LQ_ + r0 + rb) = h;
    }
}

// ---- G1: sim16 = f16(ctx16 @ qrywm16^T + scm + sqm, clamped at NEGH) ----
// 512 threads / 8 waves, per-wave 64x64 (acc[4][4] = 64 VGPR) targeting
// <=128 VGPR -> 4 waves/SIMD. Fused epilogue: row stats (rowinvl), col
// partials (pm,pl), and P16 = exp(sim - rowmax) for g23.
#define LDA1 40
__global__ __launch_bounds__(512, 4) void k_g1(
    const f16* __restrict__ ctx16, const f16* __restrict__ qrywm16,
    const float* __restrict__ scm, const float* __restrict__ sqm,
    f16* __restrict__ sim16, f16* __restrict__ p16,
    float* __restrict__ rowinvl,
    float* __restrict__ pm, float* __restrict__ pl)
{
    __shared__ f16 As[128 * LDA1];
    __shared__ f16 Bs[256 * LDA1];
    __shared__ float rowpm[4][128], rowps[4][128];
    __shared__ float colpm[2][256], colps[2][256];
    __shared__ float rowmax_s[128], colmax_s[256];
    const int b = blockIdx.z;
    const int c0 = blockIdx.x * 128;
    const int t = threadIdx.x, lane = t & 63, wv = t >> 6;
    const int wm_off = (wv >> 2) * 64, wn_off = (wv & 3) * 64;
    const f16* Ab = ctx16 + ((long long)b * LC_ + c0) * D_;
    const f16* Bb = qrywm16 + (long long)b * LQ_ * D_;
    const int srow = t >> 2, scg = (t & 3) * 8;
    f32x4 acc[4][4] = {};
    f16x8 ha, hb0, hb1;
    ha  = *(const f16x8*)(Ab + (long long)srow * D_ + scg);
    hb0 = *(const f16x8*)(Bb + (long long)srow * D_ + scg);
    hb1 = *(const f16x8*)(Bb + (long long)(srow + 128) * D_ + scg);
    for (int k0 = 0; k0 < D_; k0 += 32) {
        *(f16x8*)(As + srow * LDA1 + scg) = ha;
        *(f16x8*)(Bs + srow * LDA1 + scg) = hb0;
        *(f16x8*)(Bs + (srow + 128) * LDA1 + scg) = hb1;
        if (k0 + 32 < D_) {
            ha  = *(const f16x8*)(Ab + (long long)srow * D_ + k0 + 32 + scg);
            hb0 = *(const f16x8*)(Bb + (long long)srow * D_ + k0 + 32 + scg);
            hb1 = *(const f16x8*)(Bb + (long long)(srow + 128) * D_ + k0 + 32 + scg);
        }
        __syncthreads();
        f16x8 af[4], bf[4];
        #pragma unroll
        for (int i = 0; i < 4; ++i)
            af[i] = *(const f16x8*)(As + (wm_off + i * 16 + (lane & 15)) * LDA1 + (lane >> 4) * 8);
        #pragma unroll
        for (int j = 0; j < 4; ++j)
            bf[j] = *(const f16x8*)(Bs + (wn_off + j * 16 + (lane & 15)) * LDA1 + (lane >> 4) * 8);
        #pragma unroll
        for (int i = 0; i < 4; ++i)
            #pragma unroll
            for (int j = 0; j < 4; ++j)
                acc[i][j] = __builtin_amdgcn_mfma_f32_16x16x32_f16(af[i], bf[j], acc[i][j], 0, 0, 0);
        __syncthreads();
    }
    // ---- epilogue ----
    float sqv[4];
    #pragma unroll
    for (int j = 0; j < 4; ++j)
        sqv[j] = sqm[b * LQ_ + wn_off + j * 16 + (lane & 15)];
    float scv[4][4];
    #pragma unroll
    for (int i = 0; i < 4; ++i)
        #pragma unroll
        for (int r = 0; r < 4; ++r)
            scv[i][r] = scm[b * LC_ + c0 + wm_off + i * 16 + (lane >> 4) * 4 + r];
    float rmax[4][4], cmax[4];
    #pragma unroll
    for (int i = 0; i < 4; ++i)
        #pragma unroll
        for (int r = 0; r < 4; ++r) rmax[i][r] = -INFINITY;
    #pragma unroll
    for (int j = 0; j < 4; ++j) cmax[j] = -INFINITY;
    // pass 1: store sim16 (f16-rounded), track row/col max of rounded values
    #pragma unroll
    for (int i = 0; i < 4; ++i) {
        #pragma unroll
        for (int r = 0; r < 4; ++r) {
            int c = c0 + wm_off + i * 16 + (lane >> 4) * 4 + r;
            f16* orow = sim16 + ((long long)b * LC_ + c) * LQ_ + wn_off + (lane & 15);
            #pragma unroll
            for (int j = 0; j < 4; ++j) {
                float val = fmaxf(acc[i][j][r] + scv[i][r] + sqv[j], NEGH);
                f16 hh = (f16)val;
                orow[j * 16] = hh;
                float vr = (float)hh;
                rmax[i][r] = fmaxf(rmax[i][r], vr);
                cmax[j]    = fmaxf(cmax[j], vr);
            }
        }
    }
    #pragma unroll
    for (int i = 0; i < 4; ++i)
        #pragma unroll
        for (int r = 0; r < 4; ++r) {
            rmax[i][r] = fmaxf(rmax[i][r], __shfl_xor(rmax[i][r], 1, 64));
            rmax[i][r] = fmaxf(rmax[i][r], __shfl_xor(rmax[i][r], 2, 64));
            rmax[i][r] = fmaxf(rmax[i][r], __shfl_xor(rmax[i][r], 4, 64));
            rmax[i][r] = fmaxf(rmax[i][r], __shfl_xor(rmax[i][r], 8, 64));
        }
    #pragma unroll
    for (int j = 0; j < 4; ++j) {
        cmax[j] = fmaxf(cmax[j], __shfl_xor(cmax[j], 16, 64));
        cmax[j] = fmaxf(cmax[j], __shfl_xor(cmax[j], 32, 64));
    }
    if ((lane & 15) == 0) {
        #pragma unroll
        for (int i = 0; i < 4; ++i)
            #pragma unroll
            for (int r = 0; r < 4; ++r)
                rowpm[wv & 3][wm_off + i * 16 + (lane >> 4) * 4 + r] = rmax[i][r];
    }
    if (lane < 16) {
        #pragma unroll
        for (int j = 0; j < 4; ++j) colpm[wv >> 2][wn_off + j * 16 + lane] = cmax[j];
    }
    __syncthreads();
    if (t < 128)
        rowmax_s[t] = fmaxf(fmaxf(rowpm[0][t], rowpm[1][t]), fmaxf(rowpm[2][t], rowpm[3][t]));
    if (t < 256)
        colmax_s[t] = fmaxf(colpm[0][t], colpm[1][t]);
    __syncthreads();
    float rmf[4][4], cmf[4];
    #pragma unroll
    for (int i = 0; i < 4; ++i)
        #pragma unroll
        for (int r = 0; r < 4; ++r)
            rmf[i][r] = rowmax_s[wm_off + i * 16 + (lane >> 4) * 4 + r];
    #pragma unroll
    for (int j = 0; j < 4; ++j) cmf[j] = colmax_s[wn_off + j * 16 + (lane & 15)];
    float rsum[4][4] = {}, csum[4] = {};
    // pass 2: sums + P16 = exp(sim - rowmax)
    #pragma unroll
    for (int i = 0; i < 4; ++i) {
        #pragma unroll
        for (int r = 0; r < 4; ++r) {
            int c = c0 + wm_off + i * 16 + (lane >> 4) * 4 + r;
            f16* prow = p16 + ((long long)b * LC_ + c) * LQ_ + wn_off + (lane & 15);
            #pragma unroll
            for (int j = 0; j < 4; ++j) {
                float val = fmaxf(acc[i][j][r] + scv[i][r] + sqv[j], NEGH);
                float vr = (float)(f16)val;
                float er = __expf(vr - rmf[i][r]);
                prow[j * 16] = (f16)er;
                rsum[i][r] += er;
                csum[j]    += __expf(vr - cmf[j]);
            }
        }
    }
    #pragma unroll
    for (int i = 0; i < 4; ++i)
        #pragma unroll
        for (int r = 0; r < 4; ++r) {
            rsum[i][r] += __shfl_xor(rsum[i][r], 1, 64);
            rsum[i][r] += __shfl_xor(rsum[i][r], 2, 64);
            rsum[i][r] += __shfl_xor(rsum[i][r], 4, 64);
            rsum[i][r] += __shfl_xor(rsum[i][r], 8, 64);
        }
    #pragma unroll
    for (int j = 0; j < 4; ++j) {
        csum[j] += __shfl_xor(csum[j], 16, 64);
        csum[j] += __shfl_xor(csum[j], 32, 64);
    }
    if ((lane & 15) == 0) {
        #pragma unroll
        for (int i = 0; i < 4; ++i)
            #pragma unroll
            for (int r = 0; r < 4; ++r)
                rowps[wv & 3][wm_off + i * 16 + (lane >> 4) * 4 + r] = rsum[i][r];
    }
    if (lane < 16) {
        #pragma unroll
        for (int j = 0; j < 4; ++j) colps[wv >> 2][wn_off + j * 16 + lane] = csum[j];
    }
    __syncthreads();
    if (t < 128) {
        float l = rowps[0][t] + rowps[1][t] + rowps[2][t] + rowps[3][t];
        rowinvl[b * LC_ + c0 + t] = 1.0f / l;
    }
    if (t < 256) {
        int idx = (b * 16 + blockIdx.x) * LQ_ + t;
        pm[idx] = colmax_s[t];
        pl[idx] = colps[0][t] + colps[1][t];
    }
}

__global__ __launch_bounds__(256) void k_colreduce(
    const float* __restrict__ pm, const float* __restrict__ pl,
    float* __restrict__ colm, float* __restrict__ colinvl)
{
    const int col = blockIdx.x * 256 + threadIdx.x;
    const int b = col >> 8, q = col & 255;
    float M = -INFINITY, L = 0.f;
    for (int ch = 0; ch < 16; ++ch) {
        int idx = (b * 16 + ch) * LQ_ + q;
        float m = pm[idx], l = pl[idx];
        float nM = fmaxf(M, m);
        L = L * __expf(M - nM) + l * __expf(m - nM);
        M = nM;
    }
    colm[col] = M; colinvl[col] = 1.0f / L;
}

// ---- G3: Tpart[s][b][d][q] = sum_{c in split s} ctx[c][d]*exp(sim[c][q]-colm[q])
#define LDA3 66
#define G3SPLIT 4
#define G3CHUNK (LC_ / G3SPLIT)   // 512
__global__ __launch_bounds__(256) void k_g3(
    const f16* __restrict__ ctx16, const f16* __restrict__ sim16,
    const float* __restrict__ colm, float* __restrict__ Tpart)
{
    __shared__ f16 As[128 * LDA3];   // [d][c]
    __shared__ f16 Bs[64 * LDA3];    // [q][c]
    __shared__ float colm_s[64];
    const int b = blockIdx.x;
    const int combo = blockIdx.y;          // qt(0..3) + 4*dh(0..1)
    const int qt = combo & 3, dh = combo >> 2;
    const int q0 = qt * 64, d0 = dh * 128;
    const int cbeg = blockIdx.z * G3CHUNK;
    const int t = threadIdx.x, lane = t & 63, wv = t >> 6;
    const int wm_off = (wv >> 1) * 64, wn_off = (wv & 1) * 32;
    if (t < 64) colm_s[t] = colm[b * LQ_ + q0 + t];
    __syncthreads();
    const f16* Ab = ctx16 + (long long)b * LC_ * D_;
    const f16* Sb = sim16 + (long long)b * LC_ * LQ_;
    f32x4 acc[4][2] = {};
    const int acc_ = t >> 4, ad8 = (t & 15) * 8;   // A staging: c-row, d-col8
    const int bcc = t >> 3, bq8 = (t & 7) * 8;     // B staging: c-row, q-col8
    f16x8 ha[4], hb[2];
    #pragma unroll
    for (int p = 0; p < 4; ++p)
        ha[p] = *(const f16x8*)(Ab + (long long)(cbeg + acc_ + p * 16) * D_ + d0 + ad8);
    #pragma unroll
    for (int p = 0; p < 2; ++p)
        hb[p] = *(const f16x8*)(Sb + (long long)(cbeg + bcc + p * 32) * LQ_ + q0 + bq8);
    for (int c0 = cbeg; c0 < cbeg + G3CHUNK; c0 += 64) {
        #pragma unroll
        for (int p = 0; p < 4; ++p) {
            int cc = acc_ + p * 16;
            #pragma unroll
            for (int j = 0; j < 8; ++j)
                As[(ad8 + j) * LDA3 + cc] = ha[p][j];
        }
        #pragma unroll
        for (int p = 0; p < 2; ++p) {
            int cc = bcc + p * 32;
            #pragma unroll
            for (int j = 0; j < 8; ++j)
                Bs[(bq8 + j) * LDA3 + cc] = (f16)__expf((float)hb[p][j] - colm_s[bq8 + j]);
        }
        if (c0 + 64 < cbeg + G3CHUNK) {
            #pragma unroll
            for (int p = 0; p < 4; ++p)
                ha[p] = *(const f16x8*)(Ab + (long long)(c0 + 64 + acc_ + p * 16) * D_ + d0 + ad8);
            #pragma unroll
            for (int p = 0; p < 2; ++p)
                hb[p] = *(const f16x8*)(Sb + (long long)(c0 + 64 + bcc + p * 32) * LQ_ + q0 + bq8);
        }
        __syncthreads();
        #pragma unroll
        for (int kk = 0; kk < 64; kk += 32) {
            f16x8 af[4], bf[2];
            #pragma unroll
            for (int i = 0; i < 4; ++i)
                af[i] = *(const f16x8*)(As + (wm_off + i * 16 + (lane & 15)) * LDA3 + kk + (lane >> 4) * 8);
            #pragma unroll
            for (int j = 0; j < 2; ++j)
                bf[j] = *(const f16x8*)(Bs + (wn_off + j * 16 + (lane & 15)) * LDA3 + kk + (lane >> 4) * 8);
            #pragma unroll
            for (int i = 0; i < 4; ++i)
                #pragma unroll
                for (int j = 0; j < 2; ++j)
                    acc[i][j] = __builtin_amdgcn_mfma_f32_16x16x32_f16(af[i], bf[j], acc[i][j], 0, 0, 0);
        }
        __syncthreads();
    }
    float* Tb = Tpart + ((long long)blockIdx.z * B_ + b) * (LQ_ * D_);
    #pragma unroll
    for (int i = 0; i < 4; ++i) {
        #pragma unroll
        for (int r = 0; r < 4; ++r) {
            int d = d0 + wm_off + i * 16 + (lane >> 4) * 4 + r;
            float* orow = Tb + (long long)d * LQ_ + q0 + wn_off + (lane & 15);
            #pragma unroll
            for (int j = 0; j < 2; ++j)
                orow[j * 16] = acc[i][j][r];
        }
    }
}

// ---- BN: Bcat[256+d][q] = f16( colinvl[q] * sum_s Tpart[s][b][d][q] ) ----
__global__ __launch_bounds__(256) void k_bnorm(
    const float* __restrict__ Tpart, const float* __restrict__ colinvl,
    f16* __restrict__ Bcat)
{
    const long long i4 = ((long long)blockIdx.x * 256 + threadIdx.x) * 4;
    const int q = (int)(i4 & 255);
    const int d = (int)((i4 >> 8) & 255);
    const int b = (int)(i4 >> 16);
    float4 s = *(const float4*)(Tpart + i4);
    #pragma unroll
    for (int p = 1; p < G3SPLIT; ++p) {
        float4 v = *(const float4*)(Tpart + (long long)p * (B_ * LQ_ * D_) + i4);
        s.x += v.x; s.y += v.y; s.z += v.z; s.w += v.w;
    }
    float4 ci = *(const float4*)(colinvl + b * LQ_ + q);
    f16x4 h;
    h[0] = (f16)(s.x * ci.x); h[1] = (f16)(s.y * ci.y);
    h[2] = (f16)(s.z * ci.z); h[3] = (f16)(s.w * ci.w);
    *(f16x4*)(Bcat + (long long)b * 512 * LQ_ + (long long)(256 + d) * LQ_ + q) = h;
}

// ---- G23: [A | Bmat] = rowinvl * P16 @ Bcat^T ----
// P16 precomputed in g1 -> staging is a pure vectorized copy (no exp,
// no rowm); 128x128 tiling + register prefetch; target 4 blocks/CU.
__global__ __launch_bounds__(256, 4) void k_g23(
    const f16* __restrict__ p16, const float* __restrict__ rowinvl,
    const f16* __restrict__ Bcat,
    float* __restrict__ outA, float* __restrict__ outB)
{
    __shared__ f16 As[128 * LDA1];
    __shared__ f16 Bs[128 * LDA1];
    const int b = blockIdx.z;
    const int c0 = blockIdx.x * 128, n0 = blockIdx.y * 128;
    const int t = threadIdx.x, lane = t & 63, wv = t >> 6;
    const int wm_off = (wv >> 1) * 64, wn_off = (wv & 1) * 64;
    const f16* Ab = p16 + ((long long)b * LC_ + c0) * LQ_;
    const f16* Bb = Bcat + ((long long)b * 512 + n0) * LQ_;
    const int srow = t >> 2, scg = (t & 3) * 8;
    f32x4 acc[4][4] = {};
    f16x8 ha[2], hb[2];
    #pragma unroll
    for (int p = 0; p < 2; ++p) {
        int r = srow + p * 64;
        ha[p] = *(const f16x8*)(Ab + (long long)r * LQ_ + scg);
        hb[p] = *(const f16x8*)(Bb + (long long)r * LQ_ + scg);
    }
    for (int k0 = 0; k0 < LQ_; k0 += 32) {
        #pragma unroll
        for (int p = 0; p < 2; ++p) {
            int r = srow + p * 64;
            *(f16x8*)(As + r * LDA1 + scg) = ha[p];
            *(f16x8*)(Bs + r * LDA1 + scg) = hb[p];
        }
        if (k0 + 32 < LQ_) {
            #pragma unroll
            for (int p = 0; p < 2; ++p) {
                int r = srow + p * 64;
                ha[p] = *(const f16x8*)(Ab + (long long)r * LQ_ + k0 + 32 + scg);
                hb[p] = *(const f16x8*)(Bb + (long long)r * LQ_ + k0 + 32 + scg);
            }
        }
        __syncthreads();
        f16x8 af[4], bf[4];
        #pragma unroll
        for (int i = 0; i < 4; ++i)
            af[i] = *(const f16x8*)(As + (wm_off + i * 16 + (lane & 15)) * LDA1 + (lane >> 4) * 8);
        #pragma unroll
        for (int j = 0; j < 4; ++j)
            bf[j] = *(const f16x8*)(Bs + (wn_off + j * 16 + (lane & 15)) * LDA1 + (lane >> 4) * 8);
        #pragma unroll
        for (int i = 0; i < 4; ++i)
            #pragma unroll
            for (int j = 0; j < 4; ++j)
                acc[i][j] = __builtin_amdgcn_mfma_f32_16x16x32_f16(af[i], bf[j], acc[i][j], 0, 0, 0);
        __syncthreads();
    }
    float* outp = (n0 < 256) ? outA : outB;
    const int nbase = (n0 < 256) ? n0 : (n0 - 256);
    #pragma unroll
    for (int i = 0; i < 4; ++i) {
        #pragma unroll
        for (int r = 0; r < 4; ++r) {
            int c = c0 + wm_off + i * 16 + (lane >> 4) * 4 + r;
            float ri = rowinvl[b * LC_ + c];
            float* orow = outp + ((long long)b * LC_ + c) * D_ + nbase + wn_off + (lane & 15);
            #pragma unroll
            for (int j = 0; j < 4; ++j)
                orow[j * 16] = acc[i][j][r] * ri;
        }
    }
}

extern "C" void kernel_launch(void* const* d_in, const int* in_sizes, int n_in,
                              void* d_out, int out_size, void* d_ws, size_t ws_size,
                              hipStream_t stream) {
    const float* ctx   = (const float*)d_in[0];
    const float* qry   = (const float*)d_in[1];
    const int*   cmask = (const int*)d_in[2];
    const int*   qmask = (const int*)d_in[3];
    const float* w0    = (const float*)d_in[4];
    float* out = (float*)d_out;

    char* w = (char*)d_ws;
    float* scm     = (float*)w;  w += (long long)65536 * 4;
    float* sqm     = (float*)w;  w += (long long)8192 * 4;
    float* rowinvl = (float*)w;  w += (long long)65536 * 4;
    float* colm    = (float*)w;  w += (long long)8192 * 4;
    float* colinvl = (float*)w;  w += (long long)8192 * 4;
    float* pm      = (float*)w;  w += (long long)524288 * 4;
    float* pl      = (float*)w;  w += (long long)524288 * 4;
    f16*   sim16   = (f16*)w;    w += (long long)16777216 * 2;
    f16*   p16     = (f16*)w;    w += (long long)16777216 * 2;
    f16*   ctx16   = (f16*)w;    w += (long long)16777216 * 2;
    f16*   qrywm16 = (f16*)w;    w += (long long)2097152 * 2;
    f16*   Bcat    = (f16*)w;    w += (long long)4194304 * 2;
    float* Tpart   = (float*)w;  w += (long long)G3SPLIT * 2097152 * 4;

    k_prep<<<18432, 256, 0, stream>>>(ctx, qry, w0, cmask, qmask, ctx16, qrywm16, scm, sqm);
    k_tq<<<dim3(4, 4, 32), 256, 0, stream>>>(qry, Bcat);
    k_g1<<<dim3(16, 1, 32), 512, 0, stream>>>(ctx16, qrywm16, scm, sqm,
        sim16, p16, rowinvl, pm, pl);
    k_colreduce<<<32, 256, 0, stream>>>(pm, pl, colm, colinvl);
    k_g3<<<dim3(32, 8, G3SPLIT), 256, 0, stream>>>(ctx16, sim16, colm, Tpart);
    k_bnorm<<<2048, 256, 0, stream>>>(Tpart, colinvl, Bcat);
    k_g23<<<dim3(16, 4, 32), 256, 0, stream>>>(p16, rowinvl, Bcat,
        out, out + (long long)B_ * LC_ * D_);
}

// Round 5
// 312.626 us; speedup vs baseline: 1.0002x; 1.0002x over previous
//
#include <hip/hip_runtime.h>

#define B_  32
#define LC_ 2048
#define LQ_ 256
#define D_  256
#define NEGH (-30000.0f)   // f16-safe mask value
#define MASKF (-100000.0f) // folded-mask bias: guarantees clamp to NEGH

typedef _Float16 f16;
typedef _Float16 f16x4 __attribute__((ext_vector_type(4)));
typedef _Float16 f16x8 __attribute__((ext_vector_type(8)));
typedef float    f32x4 __attribute__((ext_vector_type(4)));

// ---- P1: qry-only prep: qrywm16 = f16(qry*wm); sqm = qry.wq (mask-folded) ----
__global__ __launch_bounds__(256) void k_prepq(
    const float* __restrict__ qry, const float* __restrict__ w0,
    const int* __restrict__ qmask,
    f16* __restrict__ qrywm16, float* __restrict__ sqm)
{
    const int lane = threadIdx.x & 63;
    const int wave = threadIdx.x >> 6;
    const int r = blockIdx.x * 4 + wave;
    float4 v = *(const float4*)(qry + (long long)r * D_ + lane * 4);
    float4 wm = *(const float4*)(w0 + 2 * D_ + lane * 4);
    f16x4 h;
    h[0] = (f16)(v.x * wm.x); h[1] = (f16)(v.y * wm.y);
    h[2] = (f16)(v.z * wm.z); h[3] = (f16)(v.w * wm.w);
    *(f16x4*)(qrywm16 + (long long)r * D_ + lane * 4) = h;
    float4 wq = *(const float4*)(w0 + D_ + lane * 4);
    float s = v.x*wq.x + v.y*wq.y + v.z*wq.z + v.w*wq.w;
    #pragma unroll
    for (int off = 32; off > 0; off >>= 1) s += __shfl_down(s, off, 64);
    if (lane == 0) sqm[r] = qmask[r] ? MASKF : s;
}

// ---- K2: transpose qry fp32 [q][d] -> f16 Bcat[0:256] rows [d][q] ----
__global__ __launch_bounds__(256) void k_tq(
    const float* __restrict__ in, f16* __restrict__ out)
{
    __shared__ float tile[64 * 65];
    const int b = blockIdx.z;
    const int r0 = blockIdx.x * 64, c0 = blockIdx.y * 64;
    const int t = threadIdx.x;
    const float* ib = in + (long long)b * LQ_ * D_;
    #pragma unroll
    for (int p = 0; p < 4; ++p) {
        int r = (t >> 4) + p * 16;
        int cb = (t & 15) * 4;
        float4 v = *(const float4*)(ib + (long long)(r0 + r) * D_ + c0 + cb);
        tile[r * 65 + cb + 0] = v.x;
        tile[r * 65 + cb + 1] = v.y;
        tile[r * 65 + cb + 2] = v.z;
        tile[r * 65 + cb + 3] = v.w;
    }
    __syncthreads();
    f16* ob = out + (long long)b * 512 * LQ_;
    #pragma unroll
    for (int p = 0; p < 4; ++p) {
        int c = (t >> 4) + p * 16;
        int rb = (t & 15) * 4;
        f16x4 h;
        h[0] = (f16)tile[(rb + 0) * 65 + c];
        h[1] = (f16)tile[(rb + 1) * 65 + c];
        h[2] = (f16)tile[(rb + 2) * 65 + c];
        h[3] = (f16)tile[(rb + 3) * 65 + c];
        *(f16x4*)(ob + (long long)(c0 + c) * LQ_ + r0 + rb) = h;
    }
}

// ---- G1: sim = ctx @ qrywm^T + scm + sqm (clamped at NEGH), from fp32 ctx.
// Single-touch ctx: stages fp32->f16, emits ctxT16[d][c] via LDS transpose
// of As (coalesced 16B stores), computes scm inline. No sim16 store: emits
// p16[c][q] = exp(sim-rowm) AND pT16[q][c], plus rowm/rowinvl and pm/pl.
#define LDA1 40
__global__ __launch_bounds__(512, 4) void k_g1(
    const float* __restrict__ ctx, const f16* __restrict__ qrywm16,
    const float* __restrict__ w0, const int* __restrict__ cmask,
    const float* __restrict__ sqm,
    f16* __restrict__ ctxT16, f16* __restrict__ p16, f16* __restrict__ pT16,
    float* __restrict__ rowm, float* __restrict__ rowinvl,
    float* __restrict__ pm, float* __restrict__ pl)
{
    __shared__ f16 As[128 * LDA1];
    __shared__ f16 Bs[256 * LDA1];
    __shared__ float wc_s[256];
    __shared__ float scm_s[128];
    __shared__ float rowpm[4][128], rowps[4][128];
    __shared__ float colpm[2][256], colps[2][256];
    __shared__ float rowmax_s[128], colmax_s[256];
    const int b = blockIdx.z;
    const int c0 = blockIdx.x * 128;
    const int t = threadIdx.x, lane = t & 63, wv = t >> 6;
    const int wm_off = (wv >> 2) * 64, wn_off = (wv & 3) * 64;
    const float* Ab = ctx + ((long long)b * LC_ + c0) * D_;
    const f16* Bb = qrywm16 + (long long)b * LQ_ * D_;
    const int srow = t >> 2, scg = (t & 3) * 8;
    const int td = t & 31, tcc = t >> 5;   // transpose-writer mapping
    if (t < 256) wc_s[t] = w0[t];
    __syncthreads();
    f32x4 acc[4][4] = {};
    float scdot = 0.f;
    for (int k0 = 0; k0 < D_; k0 += 32) {
        float4 a0 = *(const float4*)(Ab + (long long)srow * D_ + k0 + scg);
        float4 a1 = *(const float4*)(Ab + (long long)srow * D_ + k0 + scg + 4);
        f16x8 ha;
        ha[0] = (f16)a0.x; ha[1] = (f16)a0.y; ha[2] = (f16)a0.z; ha[3] = (f16)a0.w;
        ha[4] = (f16)a1.x; ha[5] = (f16)a1.y; ha[6] = (f16)a1.z; ha[7] = (f16)a1.w;
        scdot += a0.x * wc_s[k0 + scg + 0] + a0.y * wc_s[k0 + scg + 1]
               + a0.z * wc_s[k0 + scg + 2] + a0.w * wc_s[k0 + scg + 3]
               + a1.x * wc_s[k0 + scg + 4] + a1.y * wc_s[k0 + scg + 5]
               + a1.z * wc_s[k0 + scg + 6] + a1.w * wc_s[k0 + scg + 7];
        *(f16x8*)(As + srow * LDA1 + scg) = ha;
        *(f16x8*)(Bs + srow * LDA1 + scg) = *(const f16x8*)(Bb + (long long)srow * D_ + k0 + scg);
        *(f16x8*)(Bs + (srow + 128) * LDA1 + scg) = *(const f16x8*)(Bb + (long long)(srow + 128) * D_ + k0 + scg);
        __syncthreads();
        f16x8 af[4], bf[4];
        #pragma unroll
        for (int i = 0; i < 4; ++i)
            af[i] = *(const f16x8*)(As + (wm_off + i * 16 + (lane & 15)) * LDA1 + (lane >> 4) * 8);
        #pragma unroll
        for (int j = 0; j < 4; ++j)
            bf[j] = *(const f16x8*)(Bs + (wn_off + j * 16 + (lane & 15)) * LDA1 + (lane >> 4) * 8);
        #pragma unroll
        for (int i = 0; i < 4; ++i)
            #pragma unroll
            for (int j = 0; j < 4; ++j)
                acc[i][j] = __builtin_amdgcn_mfma_f32_16x16x32_f16(af[i], bf[j], acc[i][j], 0, 0, 0);
        // ctxT16 byproduct: transpose-read As (<=2-way bank alias), coalesced store
        {
            f16x8 hT;
            #pragma unroll
            for (int j = 0; j < 8; ++j)
                hT[j] = As[(tcc * 8 + j) * LDA1 + td];
            *(f16x8*)(ctxT16 + ((long long)b * D_ + k0 + td) * LC_ + c0 + tcc * 8) = hT;
        }
        __syncthreads();
    }
    // finalize scm (mask-folded) into LDS
    scdot += __shfl_xor(scdot, 1, 64);
    scdot += __shfl_xor(scdot, 2, 64);
    if ((t & 3) == 0)
        scm_s[srow] = cmask[b * LC_ + c0 + srow] ? MASKF : scdot;
    __syncthreads();
    // ---- epilogue ----
    float sqv[4];
    #pragma unroll
    for (int j = 0; j < 4; ++j)
        sqv[j] = sqm[b * LQ_ + wn_off + j * 16 + (lane & 15)];
    float scv[4][4];
    #pragma unroll
    for (int i = 0; i < 4; ++i)
        #pragma unroll
        for (int r = 0; r < 4; ++r)
            scv[i][r] = scm_s[wm_off + i * 16 + (lane >> 4) * 4 + r];
    float rmax[4][4], cmax[4];
    #pragma unroll
    for (int i = 0; i < 4; ++i)
        #pragma unroll
        for (int r = 0; r < 4; ++r) rmax[i][r] = -INFINITY;
    #pragma unroll
    for (int j = 0; j < 4; ++j) cmax[j] = -INFINITY;
    // pass 1: track row/col max of f16-rounded values (no sim store)
    #pragma unroll
    for (int i = 0; i < 4; ++i) {
        #pragma unroll
        for (int r = 0; r < 4; ++r) {
            #pragma unroll
            for (int j = 0; j < 4; ++j) {
                float val = fmaxf(acc[i][j][r] + scv[i][r] + sqv[j], NEGH);
                float vr = (float)(f16)val;
                rmax[i][r] = fmaxf(rmax[i][r], vr);
                cmax[j]    = fmaxf(cmax[j], vr);
            }
        }
    }
    #pragma unroll
    for (int i = 0; i < 4; ++i)
        #pragma unroll
        for (int r = 0; r < 4; ++r) {
            rmax[i][r] = fmaxf(rmax[i][r], __shfl_xor(rmax[i][r], 1, 64));
            rmax[i][r] = fmaxf(rmax[i][r], __shfl_xor(rmax[i][r], 2, 64));
            rmax[i][r] = fmaxf(rmax[i][r], __shfl_xor(rmax[i][r], 4, 64));
            rmax[i][r] = fmaxf(rmax[i][r], __shfl_xor(rmax[i][r], 8, 64));
        }
    #pragma unroll
    for (int j = 0; j < 4; ++j) {
        cmax[j] = fmaxf(cmax[j], __shfl_xor(cmax[j], 16, 64));
        cmax[j] = fmaxf(cmax[j], __shfl_xor(cmax[j], 32, 64));
    }
    if ((lane & 15) == 0) {
        #pragma unroll
        for (int i = 0; i < 4; ++i)
            #pragma unroll
            for (int r = 0; r < 4; ++r)
                rowpm[wv & 3][wm_off + i * 16 + (lane >> 4) * 4 + r] = rmax[i][r];
    }
    if (lane < 16) {
        #pragma unroll
        for (int j = 0; j < 4; ++j) colpm[wv >> 2][wn_off + j * 16 + lane] = cmax[j];
    }
    __syncthreads();
    if (t < 128)
        rowmax_s[t] = fmaxf(fmaxf(rowpm[0][t], rowpm[1][t]), fmaxf(rowpm[2][t], rowpm[3][t]));
    if (t < 256)
        colmax_s[t] = fmaxf(colpm[0][t], colpm[1][t]);
    __syncthreads();
    float rmf[4][4], cmf[4];
    #pragma unroll
    for (int i = 0; i < 4; ++i)
        #pragma unroll
        for (int r = 0; r < 4; ++r)
            rmf[i][r] = rowmax_s[wm_off + i * 16 + (lane >> 4) * 4 + r];
    #pragma unroll
    for (int j = 0; j < 4; ++j) cmf[j] = colmax_s[wn_off + j * 16 + (lane & 15)];
    float rsum[4][4] = {}, csum[4] = {};
    // pass 2: sums + store p16[c][q] and pT16[q][c]
    #pragma unroll
    for (int i = 0; i < 4; ++i) {
        #pragma unroll
        for (int r = 0; r < 4; ++r) {
            int c = c0 + wm_off + i * 16 + (lane >> 4) * 4 + r;
            f16* prow = p16 + ((long long)b * LC_ + c) * LQ_ + wn_off + (lane & 15);
            #pragma unroll
            for (int j = 0; j < 4; ++j) {
                int q = wn_off + j * 16 + (lane & 15);
                float val = fmaxf(acc[i][j][r] + scv[i][r] + sqv[j], NEGH);
                float vr = (float)(f16)val;
                float er = __expf(vr - rmf[i][r]);
                f16 hp = (f16)er;
                prow[j * 16] = hp;
                pT16[((long long)b * LQ_ + q) * LC_ + c] = hp;
                rsum[i][r] += er;
                csum[j]    += __expf(vr - cmf[j]);
            }
        }
    }
    #pragma unroll
    for (int i = 0; i < 4; ++i)
        #pragma unroll
        for (int r = 0; r < 4; ++r) {
            rsum[i][r] += __shfl_xor(rsum[i][r], 1, 64);
            rsum[i][r] += __shfl_xor(rsum[i][r], 2, 64);
            rsum[i][r] += __shfl_xor(rsum[i][r], 4, 64);
            rsum[i][r] += __shfl_xor(rsum[i][r], 8, 64);
        }
    #pragma unroll
    for (int j = 0; j < 4; ++j) {
        csum[j] += __shfl_xor(csum[j], 16, 64);
        csum[j] += __shfl_xor(csum[j], 32, 64);
    }
    if ((lane & 15) == 0) {
        #pragma unroll
        for (int i = 0; i < 4; ++i)
            #pragma unroll
            for (int r = 0; r < 4; ++r)
                rowps[wv & 3][wm_off + i * 16 + (lane >> 4) * 4 + r] = rsum[i][r];
    }
    if (lane < 16) {
        #pragma unroll
        for (int j = 0; j < 4; ++j) colps[wv >> 2][wn_off + j * 16 + lane] = csum[j];
    }
    __syncthreads();
    if (t < 128) {
        float l = rowps[0][t] + rowps[1][t] + rowps[2][t] + rowps[3][t];
        rowm[b * LC_ + c0 + t]    = rowmax_s[t];
        rowinvl[b * LC_ + c0 + t] = 1.0f / l;
    }
    if (t < 256) {
        int idx = (b * 16 + blockIdx.x) * LQ_ + t;
        pm[idx] = colmax_s[t];
        pl[idx] = colps[0][t] + colps[1][t];
    }
}

__global__ __launch_bounds__(256) void k_colreduce(
    const float* __restrict__ pm, const float* __restrict__ pl,
    float* __restrict__ colm, float* __restrict__ colinvl)
{
    const int col = blockIdx.x * 256 + threadIdx.x;
    const int b = col >> 8, q = col & 255;
    float M = -INFINITY, L = 0.f;
    for (int ch = 0; ch < 16; ++ch) {
        int idx = (b * 16 + ch) * LQ_ + q;
        float m = pm[idx], l = pl[idx];
        float nM = fmaxf(M, m);
        L = L * __expf(M - nM) + l * __expf(m - nM);
        M = nM;
    }
    colm[col] = M; colinvl[col] = 1.0f / L;
}

// ---- G3: Tpart[s][b][d][q] = sum_c ctxT16[d][c] * (p16[c][q]*exp(rowm[c]-colm[q]))
// Both operands K(=c)-major -> pure vectorized GEMM staging (no transposes).
// Fully-masked column (colm < -29000): numerator == 1 for every c.
#define LDA3 72
#define G3SPLIT 4
#define G3CHUNK (LC_ / G3SPLIT)   // 512
__global__ __launch_bounds__(256) void k_g3(
    const f16* __restrict__ ctxT16, const f16* __restrict__ pT16,
    const float* __restrict__ rowm, const float* __restrict__ colm,
    float* __restrict__ Tpart)
{
    __shared__ f16 As[128 * LDA3];   // [d][c]
    __shared__ f16 Bs[64 * LDA3];    // [q][c]
    __shared__ float rowm_s[G3CHUNK];
    __shared__ float colm_s[64];
    const int b = blockIdx.x;
    const int combo = blockIdx.y;          // qt(0..3) + 4*dh(0..1)
    const int qt = combo & 3, dh = combo >> 2;
    const int q0 = qt * 64, d0 = dh * 128;
    const int cbeg = blockIdx.z * G3CHUNK;
    const int t = threadIdx.x, lane = t & 63, wv = t >> 6;
    const int wm_off = (wv >> 1) * 64, wn_off = (wv & 1) * 32;
    for (int i = t; i < G3CHUNK; i += 256) rowm_s[i] = rowm[b * LC_ + cbeg + i];
    if (t < 64) colm_s[t] = colm[b * LQ_ + q0 + t];
    __syncthreads();
    const f16* Ab = ctxT16 + ((long long)b * D_ + d0) * LC_;
    const f16* Pb = pT16 + ((long long)b * LQ_ + q0) * LC_;
    const int ar = t >> 3, acg = (t & 7) * 8;   // row 0..31 (+32p), c-col8
    f32x4 acc[4][2] = {};
    f16x8 ha[4], hb[2];
    #pragma unroll
    for (int p = 0; p < 4; ++p)
        ha[p] = *(const f16x8*)(Ab + (long long)(ar + p * 32) * LC_ + cbeg + acg);
    #pragma unroll
    for (int p = 0; p < 2; ++p)
        hb[p] = *(const f16x8*)(Pb + (long long)(ar + p * 32) * LC_ + cbeg + acg);
    for (int c0 = cbeg; c0 < cbeg + G3CHUNK; c0 += 64) {
        #pragma unroll
        for (int p = 0; p < 4; ++p)
            *(f16x8*)(As + (ar + p * 32) * LDA3 + acg) = ha[p];
        #pragma unroll
        for (int p = 0; p < 2; ++p) {
            float cmq = colm_s[ar + p * 32];
            f16x8 e;
            if (cmq < -29000.f) {
                #pragma unroll
                for (int j = 0; j < 8; ++j) e[j] = (f16)1.0f;
            } else {
                #pragma unroll
                for (int j = 0; j < 8; ++j)
                    e[j] = (f16)((float)hb[p][j] * __expf(rowm_s[(c0 - cbeg) + acg + j] - cmq));
            }
            *(f16x8*)(Bs + (ar + p * 32) * LDA3 + acg) = e;
        }
        if (c0 + 64 < cbeg + G3CHUNK) {
            #pragma unroll
            for (int p = 0; p < 4; ++p)
                ha[p] = *(const f16x8*)(Ab + (long long)(ar + p * 32) * LC_ + c0 + 64 + acg);
            #pragma unroll
            for (int p = 0; p < 2; ++p)
                hb[p] = *(const f16x8*)(Pb + (long long)(ar + p * 32) * LC_ + c0 + 64 + acg);
        }
        __syncthreads();
        #pragma unroll
        for (int kk = 0; kk < 64; kk += 32) {
            f16x8 af[4], bf[2];
            #pragma unroll
            for (int i = 0; i < 4; ++i)
                af[i] = *(const f16x8*)(As + (wm_off + i * 16 + (lane & 15)) * LDA3 + kk + (lane >> 4) * 8);
            #pragma unroll
            for (int j = 0; j < 2; ++j)
                bf[j] = *(const f16x8*)(Bs + (wn_off + j * 16 + (lane & 15)) * LDA3 + kk + (lane >> 4) * 8);
            #pragma unroll
            for (int i = 0; i < 4; ++i)
                #pragma unroll
                for (int j = 0; j < 2; ++j)
                    acc[i][j] = __builtin_amdgcn_mfma_f32_16x16x32_f16(af[i], bf[j], acc[i][j], 0, 0, 0);
        }
        __syncthreads();
    }
    float* Tb = Tpart + ((long long)blockIdx.z * B_ + b) * (LQ_ * D_);
    #pragma unroll
    for (int i = 0; i < 4; ++i) {
        #pragma unroll
        for (int r = 0; r < 4; ++r) {
            int d = d0 + wm_off + i * 16 + (lane >> 4) * 4 + r;
            float* orow = Tb + (long long)d * LQ_ + q0 + wn_off + (lane & 15);
            #pragma unroll
            for (int j = 0; j < 2; ++j)
                orow[j * 16] = acc[i][j][r];
        }
    }
}

// ---- BN: Bcat[256+d][q] = f16( colinvl[q] * sum_s Tpart[s][b][d][q] ) ----
__global__ __launch_bounds__(256) void k_bnorm(
    const float* __restrict__ Tpart, const float* __restrict__ colinvl,
    f16* __restrict__ Bcat)
{
    const long long i4 = ((long long)blockIdx.x * 256 + threadIdx.x) * 4;
    const int q = (int)(i4 & 255);
    const int d = (int)((i4 >> 8) & 255);
    const int b = (int)(i4 >> 16);
    float4 s = *(const float4*)(Tpart + i4);
    #pragma unroll
    for (int p = 1; p < G3SPLIT; ++p) {
        float4 v = *(const float4*)(Tpart + (long long)p * (B_ * LQ_ * D_) + i4);
        s.x += v.x; s.y += v.y; s.z += v.z; s.w += v.w;
    }
    float4 ci = *(const float4*)(colinvl + b * LQ_ + q);
    f16x4 h;
    h[0] = (f16)(s.x * ci.x); h[1] = (f16)(s.y * ci.y);
    h[2] = (f16)(s.z * ci.z); h[3] = (f16)(s.w * ci.w);
    *(f16x4*)(Bcat + (long long)b * 512 * LQ_ + (long long)(256 + d) * LQ_ + q) = h;
}

// ---- G23: [A | Bmat] = rowinvl * P16 @ Bcat^T ----
__global__ __launch_bounds__(256, 4) void k_g23(
    const f16* __restrict__ p16, const float* __restrict__ rowinvl,
    const f16* __restrict__ Bcat,
    float* __restrict__ outA, float* __restrict__ outB)
{
    __shared__ f16 As[128 * LDA1];
    __shared__ f16 Bs[128 * LDA1];
    const int b = blockIdx.z;
    const int c0 = blockIdx.x * 128, n0 = blockIdx.y * 128;
    const int t = threadIdx.x, lane = t & 63, wv = t >> 6;
    const int wm_off = (wv >> 1) * 64, wn_off = (wv & 1) * 64;
    const f16* Ab = p16 + ((long long)b * LC_ + c0) * LQ_;
    const f16* Bb = Bcat + ((long long)b * 512 + n0) * LQ_;
    const int srow = t >> 2, scg = (t & 3) * 8;
    f32x4 acc[4][4] = {};
    f16x8 ha[2], hb[2];
    #pragma unroll
    for (int p = 0; p < 2; ++p) {
        int r = srow + p * 64;
        ha[p] = *(const f16x8*)(Ab + (long long)r * LQ_ + scg);
        hb[p] = *(const f16x8*)(Bb + (long long)r * LQ_ + scg);
    }
    for (int k0 = 0; k0 < LQ_; k0 += 32) {
        #pragma unroll
        for (int p = 0; p < 2; ++p) {
            int r = srow + p * 64;
            *(f16x8*)(As + r * LDA1 + scg) = ha[p];
            *(f16x8*)(Bs + r * LDA1 + scg) = hb[p];
        }
        if (k0 + 32 < LQ_) {
            #pragma unroll
            for (int p = 0; p < 2; ++p) {
                int r = srow + p * 64;
                ha[p] = *(const f16x8*)(Ab + (long long)r * LQ_ + k0 + 32 + scg);
                hb[p] = *(const f16x8*)(Bb + (long long)r * LQ_ + k0 + 32 + scg);
            }
        }
        __syncthreads();
        f16x8 af[4], bf[4];
        #pragma unroll
        for (int i = 0; i < 4; ++i)
            af[i] = *(const f16x8*)(As + (wm_off + i * 16 + (lane & 15)) * LDA1 + (lane >> 4) * 8);
        #pragma unroll
        for (int j = 0; j < 4; ++j)
            bf[j] = *(const f16x8*)(Bs + (wn_off + j * 16 + (lane & 15)) * LDA1 + (lane >> 4) * 8);
        #pragma unroll
        for (int i = 0; i < 4; ++i)
            #pragma unroll
            for (int j = 0; j < 4; ++j)
                acc[i][j] = __builtin_amdgcn_mfma_f32_16x16x32_f16(af[i], bf[j], acc[i][j], 0, 0, 0);
        __syncthreads();
    }
    float* outp = (n0 < 256) ? outA : outB;
    const int nbase = (n0 < 256) ? n0 : (n0 - 256);
    #pragma unroll
    for (int i = 0; i < 4; ++i) {
        #pragma unroll
        for (int r = 0; r < 4; ++r) {
            int c = c0 + wm_off + i * 16 + (lane >> 4) * 4 + r;
            float ri = rowinvl[b * LC_ + c];
            float* orow = outp + ((long long)b * LC_ + c) * D_ + nbase + wn_off + (lane & 15);
            #pragma unroll
            for (int j = 0; j < 4; ++j)
                orow[j * 16] = acc[i][j][r] * ri;
        }
    }
}

extern "C" void kernel_launch(void* const* d_in, const int* in_sizes, int n_in,
                              void* d_out, int out_size, void* d_ws, size_t ws_size,
                              hipStream_t stream) {
    const float* ctx   = (const float*)d_in[0];
    const float* qry   = (const float*)d_in[1];
    const int*   cmask = (const int*)d_in[2];
    const int*   qmask = (const int*)d_in[3];
    const float* w0    = (const float*)d_in[4];
    float* out = (float*)d_out;

    char* w = (char*)d_ws;
    float* sqm     = (float*)w;  w += (long long)8192 * 4;
    float* rowm    = (float*)w;  w += (long long)65536 * 4;
    float* rowinvl = (float*)w;  w += (long long)65536 * 4;
    float* colm    = (float*)w;  w += (long long)8192 * 4;
    float* colinvl = (float*)w;  w += (long long)8192 * 4;
    float* pm      = (float*)w;  w += (long long)524288 * 4;
    float* pl      = (float*)w;  w += (long long)524288 * 4;
    f16*   p16     = (f16*)w;    w += (long long)16777216 * 2;
    f16*   pT16    = (f16*)w;    w += (long long)16777216 * 2;
    f16*   ctxT16  = (f16*)w;    w += (long long)16777216 * 2;
    f16*   qrywm16 = (f16*)w;    w += (long long)2097152 * 2;
    f16*   Bcat    = (f16*)w;    w += (long long)4194304 * 2;
    float* Tpart   = (float*)w;  w += (long long)G3SPLIT * 2097152 * 4;

    k_prepq<<<2048, 256, 0, stream>>>(qry, w0, qmask, qrywm16, sqm);
    k_tq<<<dim3(4, 4, 32), 256, 0, stream>>>(qry, Bcat);
    k_g1<<<dim3(16, 1, 32), 512, 0, stream>>>(ctx, qrywm16, w0, cmask, sqm,
        ctxT16, p16, pT16, rowm, rowinvl, pm, pl);
    k_colreduce<<<32, 256, 0, stream>>>(pm, pl, colm, colinvl);
    k_g3<<<dim3(32, 8, G3SPLIT), 256, 0, stream>>>(ctxT16, pT16, rowm, colm, Tpart);
    k_bnorm<<<2048, 256, 0, stream>>>(Tpart, colinvl, Bcat);
    k_g23<<<dim3(16, 4, 32), 256, 0, stream>>>(p16, rowinvl, Bcat,
        out, out + (long long)B_ * LC_ * D_);
}

// Round 6
// 309.661 us; speedup vs baseline: 1.0098x; 1.0096x over previous
//
#include <hip/hip_runtime.h>

#define B_  32
#define LC_ 2048
#define LQ_ 256
#define D_  256
#define NEGH (-30000.0f)   // f16-safe mask value
#define MASKF (-100000.0f) // folded-mask bias: guarantees clamp to NEGH

typedef _Float16 f16;
typedef _Float16 f16x4 __attribute__((ext_vector_type(4)));
typedef _Float16 f16x8 __attribute__((ext_vector_type(8)));
typedef float    f32x4 __attribute__((ext_vector_type(4)));

// ---- P1: qry-only prep: qrywm16 = f16(qry*wm); sqm = qry.wq (mask-folded) ----
__global__ __launch_bounds__(256) void k_prepq(
    const float* __restrict__ qry, const float* __restrict__ w0,
    const int* __restrict__ qmask,
    f16* __restrict__ qrywm16, float* __restrict__ sqm)
{
    const int lane = threadIdx.x & 63;
    const int wave = threadIdx.x >> 6;
    const int r = blockIdx.x * 4 + wave;
    float4 v = *(const float4*)(qry + (long long)r * D_ + lane * 4);
    float4 wm = *(const float4*)(w0 + 2 * D_ + lane * 4);
    f16x4 h;
    h[0] = (f16)(v.x * wm.x); h[1] = (f16)(v.y * wm.y);
    h[2] = (f16)(v.z * wm.z); h[3] = (f16)(v.w * wm.w);
    *(f16x4*)(qrywm16 + (long long)r * D_ + lane * 4) = h;
    float4 wq = *(const float4*)(w0 + D_ + lane * 4);
    float s = v.x*wq.x + v.y*wq.y + v.z*wq.z + v.w*wq.w;
    #pragma unroll
    for (int off = 32; off > 0; off >>= 1) s += __shfl_down(s, off, 64);
    if (lane == 0) sqm[r] = qmask[r] ? MASKF : s;
}

// ---- K2: transpose qry fp32 [q][d] -> f16 Bcat[0:256] rows [d][q] ----
__global__ __launch_bounds__(256) void k_tq(
    const float* __restrict__ in, f16* __restrict__ out)
{
    __shared__ float tile[64 * 65];
    const int b = blockIdx.z;
    const int r0 = blockIdx.x * 64, c0 = blockIdx.y * 64;
    const int t = threadIdx.x;
    const float* ib = in + (long long)b * LQ_ * D_;
    #pragma unroll
    for (int p = 0; p < 4; ++p) {
        int r = (t >> 4) + p * 16;
        int cb = (t & 15) * 4;
        float4 v = *(const float4*)(ib + (long long)(r0 + r) * D_ + c0 + cb);
        tile[r * 65 + cb + 0] = v.x;
        tile[r * 65 + cb + 1] = v.y;
        tile[r * 65 + cb + 2] = v.z;
        tile[r * 65 + cb + 3] = v.w;
    }
    __syncthreads();
    f16* ob = out + (long long)b * 512 * LQ_;
    #pragma unroll
    for (int p = 0; p < 4; ++p) {
        int c = (t >> 4) + p * 16;
        int rb = (t & 15) * 4;
        f16x4 h;
        h[0] = (f16)tile[(rb + 0) * 65 + c];
        h[1] = (f16)tile[(rb + 1) * 65 + c];
        h[2] = (f16)tile[(rb + 2) * 65 + c];
        h[3] = (f16)tile[(rb + 3) * 65 + c];
        *(f16x4*)(ob + (long long)(c0 + c) * LQ_ + r0 + rb) = h;
    }
}

// ---- G1: sim = ctx @ qrywm^T + scm + sqm (clamped at NEGH), from fp32 ctx.
// Single-touch ctx: stages fp32->f16, emits ctxT16[d][c] via LDS transpose
// of As (coalesced 16B stores), computes scm inline. No sim16 store: emits
// p16[c][q] = exp(sim-rowm) AND pT16[q][c], plus rowm/rowinvl and pm/pl.
#define LDA1 40
__global__ __launch_bounds__(512, 4) void k_g1(
    const float* __restrict__ ctx, const f16* __restrict__ qrywm16,
    const float* __restrict__ w0, const int* __restrict__ cmask,
    const float* __restrict__ sqm,
    f16* __restrict__ ctxT16, f16* __restrict__ p16, f16* __restrict__ pT16,
    float* __restrict__ rowm, float* __restrict__ rowinvl,
    float* __restrict__ pm, float* __restrict__ pl)
{
    __shared__ f16 As[128 * LDA1];
    __shared__ f16 Bs[256 * LDA1];
    __shared__ float wc_s[256];
    __shared__ float scm_s[128];
    __shared__ float rowpm[4][128], rowps[4][128];
    __shared__ float colpm[2][256], colps[2][256];
    __shared__ float rowmax_s[128], colmax_s[256];
    const int b = blockIdx.z;
    const int c0 = blockIdx.x * 128;
    const int t = threadIdx.x, lane = t & 63, wv = t >> 6;
    const int wm_off = (wv >> 2) * 64, wn_off = (wv & 3) * 64;
    const float* Ab = ctx + ((long long)b * LC_ + c0) * D_;
    const f16* Bb = qrywm16 + (long long)b * LQ_ * D_;
    const int srow = t >> 2, scg = (t & 3) * 8;
    const int td = t & 31, tcc = t >> 5;   // transpose-writer mapping
    if (t < 256) wc_s[t] = w0[t];
    __syncthreads();
    f32x4 acc[4][4] = {};
    float scdot = 0.f;
    for (int k0 = 0; k0 < D_; k0 += 32) {
        float4 a0 = *(const float4*)(Ab + (long long)srow * D_ + k0 + scg);
        float4 a1 = *(const float4*)(Ab + (long long)srow * D_ + k0 + scg + 4);
        f16x8 ha;
        ha[0] = (f16)a0.x; ha[1] = (f16)a0.y; ha[2] = (f16)a0.z; ha[3] = (f16)a0.w;
        ha[4] = (f16)a1.x; ha[5] = (f16)a1.y; ha[6] = (f16)a1.z; ha[7] = (f16)a1.w;
        scdot += a0.x * wc_s[k0 + scg + 0] + a0.y * wc_s[k0 + scg + 1]
               + a0.z * wc_s[k0 + scg + 2] + a0.w * wc_s[k0 + scg + 3]
               + a1.x * wc_s[k0 + scg + 4] + a1.y * wc_s[k0 + scg + 5]
               + a1.z * wc_s[k0 + scg + 6] + a1.w * wc_s[k0 + scg + 7];
        *(f16x8*)(As + srow * LDA1 + scg) = ha;
        *(f16x8*)(Bs + srow * LDA1 + scg) = *(const f16x8*)(Bb + (long long)srow * D_ + k0 + scg);
        *(f16x8*)(Bs + (srow + 128) * LDA1 + scg) = *(const f16x8*)(Bb + (long long)(srow + 128) * D_ + k0 + scg);
        __syncthreads();
        f16x8 af[4], bf[4];
        #pragma unroll
        for (int i = 0; i < 4; ++i)
            af[i] = *(const f16x8*)(As + (wm_off + i * 16 + (lane & 15)) * LDA1 + (lane >> 4) * 8);
        #pragma unroll
        for (int j = 0; j < 4; ++j)
            bf[j] = *(const f16x8*)(Bs + (wn_off + j * 16 + (lane & 15)) * LDA1 + (lane >> 4) * 8);
        #pragma unroll
        for (int i = 0; i < 4; ++i)
            #pragma unroll
            for (int j = 0; j < 4; ++j)
                acc[i][j] = __builtin_amdgcn_mfma_f32_16x16x32_f16(af[i], bf[j], acc[i][j], 0, 0, 0);
        // ctxT16 byproduct: transpose-read As (<=2-way bank alias), coalesced store
        {
            f16x8 hT;
            #pragma unroll
            for (int j = 0; j < 8; ++j)
                hT[j] = As[(tcc * 8 + j) * LDA1 + td];
            *(f16x8*)(ctxT16 + ((long long)b * D_ + k0 + td) * LC_ + c0 + tcc * 8) = hT;
        }
        __syncthreads();
    }
    // finalize scm (mask-folded) into LDS
    scdot += __shfl_xor(scdot, 1, 64);
    scdot += __shfl_xor(scdot, 2, 64);
    if ((t & 3) == 0)
        scm_s[srow] = cmask[b * LC_ + c0 + srow] ? MASKF : scdot;
    __syncthreads();
    // ---- epilogue ----
    float sqv[4];
    #pragma unroll
    for (int j = 0; j < 4; ++j)
        sqv[j] = sqm[b * LQ_ + wn_off + j * 16 + (lane & 15)];
    float scv[4][4];
    #pragma unroll
    for (int i = 0; i < 4; ++i)
        #pragma unroll
        for (int r = 0; r < 4; ++r)
            scv[i][r] = scm_s[wm_off + i * 16 + (lane >> 4) * 4 + r];
    float rmax[4][4], cmax[4];
    #pragma unroll
    for (int i = 0; i < 4; ++i)
        #pragma unroll
        for (int r = 0; r < 4; ++r) rmax[i][r] = -INFINITY;
    #pragma unroll
    for (int j = 0; j < 4; ++j) cmax[j] = -INFINITY;
    // pass 1: track row/col max of f16-rounded values (no sim store)
    #pragma unroll
    for (int i = 0; i < 4; ++i) {
        #pragma unroll
        for (int r = 0; r < 4; ++r) {
            #pragma unroll
            for (int j = 0; j < 4; ++j) {
                float val = fmaxf(acc[i][j][r] + scv[i][r] + sqv[j], NEGH);
                float vr = (float)(f16)val;
                rmax[i][r] = fmaxf(rmax[i][r], vr);
                cmax[j]    = fmaxf(cmax[j], vr);
            }
        }
    }
    #pragma unroll
    for (int i = 0; i < 4; ++i)
        #pragma unroll
        for (int r = 0; r < 4; ++r) {
            rmax[i][r] = fmaxf(rmax[i][r], __shfl_xor(rmax[i][r], 1, 64));
            rmax[i][r] = fmaxf(rmax[i][r], __shfl_xor(rmax[i][r], 2, 64));
            rmax[i][r] = fmaxf(rmax[i][r], __shfl_xor(rmax[i][r], 4, 64));
            rmax[i][r] = fmaxf(rmax[i][r], __shfl_xor(rmax[i][r], 8, 64));
        }
    #pragma unroll
    for (int j = 0; j < 4; ++j) {
        cmax[j] = fmaxf(cmax[j], __shfl_xor(cmax[j], 16, 64));
        cmax[j] = fmaxf(cmax[j], __shfl_xor(cmax[j], 32, 64));
    }
    if ((lane & 15) == 0) {
        #pragma unroll
        for (int i = 0; i < 4; ++i)
            #pragma unroll
            for (int r = 0; r < 4; ++r)
                rowpm[wv & 3][wm_off + i * 16 + (lane >> 4) * 4 + r] = rmax[i][r];
    }
    if (lane < 16) {
        #pragma unroll
        for (int j = 0; j < 4; ++j) colpm[wv >> 2][wn_off + j * 16 + lane] = cmax[j];
    }
    __syncthreads();
    if (t < 128)
        rowmax_s[t] = fmaxf(fmaxf(rowpm[0][t], rowpm[1][t]), fmaxf(rowpm[2][t], rowpm[3][t]));
    if (t < 256)
        colmax_s[t] = fmaxf(colpm[0][t], colpm[1][t]);
    __syncthreads();
    float rmf[4][4], cmf[4];
    #pragma unroll
    for (int i = 0; i < 4; ++i)
        #pragma unroll
        for (int r = 0; r < 4; ++r)
            rmf[i][r] = rowmax_s[wm_off + i * 16 + (lane >> 4) * 4 + r];
    #pragma unroll
    for (int j = 0; j < 4; ++j) cmf[j] = colmax_s[wn_off + j * 16 + (lane & 15)];
    float rsum[4][4] = {}, csum[4] = {};
    // pass 2: sums + store p16[c][q] and pT16[q][c]
    #pragma unroll
    for (int i = 0; i < 4; ++i) {
        #pragma unroll
        for (int r = 0; r < 4; ++r) {
            int c = c0 + wm_off + i * 16 + (lane >> 4) * 4 + r;
            f16* prow = p16 + ((long long)b * LC_ + c) * LQ_ + wn_off + (lane & 15);
            #pragma unroll
            for (int j = 0; j < 4; ++j) {
                int q = wn_off + j * 16 + (lane & 15);
                float val = fmaxf(acc[i][j][r] + scv[i][r] + sqv[j], NEGH);
                float vr = (float)(f16)val;
                float er = __expf(vr - rmf[i][r]);
                f16 hp = (f16)er;
                prow[j * 16] = hp;
                pT16[((long long)b * LQ_ + q) * LC_ + c] = hp;
                rsum[i][r] += er;
                csum[j]    += __expf(vr - cmf[j]);
            }
        }
    }
    #pragma unroll
    for (int i = 0; i < 4; ++i)
        #pragma unroll
        for (int r = 0; r < 4; ++r) {
            rsum[i][r] += __shfl_xor(rsum[i][r], 1, 64);
            rsum[i][r] += __shfl_xor(rsum[i][r], 2, 64);
            rsum[i][r] += __shfl_xor(rsum[i][r], 4, 64);
            rsum[i][r] += __shfl_xor(rsum[i][r], 8, 64);
        }
    #pragma unroll
    for (int j = 0; j < 4; ++j) {
        csum[j] += __shfl_xor(csum[j], 16, 64);
        csum[j] += __shfl_xor(csum[j], 32, 64);
    }
    if ((lane & 15) == 0) {
        #pragma unroll
        for (int i = 0; i < 4; ++i)
            #pragma unroll
            for (int r = 0; r < 4; ++r)
                rowps[wv & 3][wm_off + i * 16 + (lane >> 4) * 4 + r] = rsum[i][r];
    }
    if (lane < 16) {
        #pragma unroll
        for (int j = 0; j < 4; ++j) colps[wv >> 2][wn_off + j * 16 + lane] = csum[j];
    }
    __syncthreads();
    if (t < 128) {
        float l = rowps[0][t] + rowps[1][t] + rowps[2][t] + rowps[3][t];
        rowm[b * LC_ + c0 + t]    = rowmax_s[t];
        rowinvl[b * LC_ + c0 + t] = 1.0f / l;
    }
    if (t < 256) {
        int idx = (b * 16 + blockIdx.x) * LQ_ + t;
        pm[idx] = colmax_s[t];
        pl[idx] = colps[0][t] + colps[1][t];
    }
}

__global__ __launch_bounds__(256) void k_colreduce(
    const float* __restrict__ pm, const float* __restrict__ pl,
    float* __restrict__ colm, float* __restrict__ colinvl)
{
    const int col = blockIdx.x * 256 + threadIdx.x;
    const int b = col >> 8, q = col & 255;
    float M = -INFINITY, L = 0.f;
    for (int ch = 0; ch < 16; ++ch) {
        int idx = (b * 16 + ch) * LQ_ + q;
        float m = pm[idx], l = pl[idx];
        float nM = fmaxf(M, m);
        L = L * __expf(M - nM) + l * __expf(m - nM);
        M = nM;
    }
    colm[col] = M; colinvl[col] = 1.0f / L;
}

// ---- G3: Tpart[s][b][d][q] = sum_c ctxT16[d][c] * (p16[c][q]*exp(rowm[c]-colm[q]))
// Retiled 128d x 128q x 512thr (was 128x64x256): ctxT16 re-reads x4 -> x2.
// Flat grid 512 with bijective XCD swizzle. Both operands K-major.
#define LDA3 72
#define G3SPLIT 4
#define G3CHUNK (LC_ / G3SPLIT)   // 512
__global__ __launch_bounds__(512) void k_g3(
    const f16* __restrict__ ctxT16, const f16* __restrict__ pT16,
    const float* __restrict__ rowm, const float* __restrict__ colm,
    float* __restrict__ Tpart)
{
    __shared__ f16 As[128 * LDA3];   // [d][c]
    __shared__ f16 Bs[128 * LDA3];   // [q][c]
    __shared__ float rowm_s[G3CHUNK];
    __shared__ float colm_s[128];
    // bijective XCD swizzle: 512 blocks = 8 XCD x 64
    const int lin = blockIdx.x;
    const int swz = (lin & 7) * 64 + (lin >> 3);
    const int combo = swz & 3;             // qt(0..1) + 2*dh(0..1)
    const int split = (swz >> 2) & 3;
    const int b = swz >> 4;
    const int qt = combo & 1, dh = combo >> 1;
    const int q0 = qt * 128, d0 = dh * 128;
    const int cbeg = split * G3CHUNK;
    const int t = threadIdx.x, lane = t & 63, wv = t >> 6;
    const int wm_off = (wv >> 2) * 64, wn_off = (wv & 3) * 32;
    if (t < G3CHUNK) rowm_s[t] = rowm[b * LC_ + cbeg + t];
    if (t < 128) colm_s[t] = colm[b * LQ_ + q0 + t];
    __syncthreads();
    const f16* Ab = ctxT16 + ((long long)b * D_ + d0) * LC_;
    const f16* Pb = pT16 + ((long long)b * LQ_ + q0) * LC_;
    const int ar = t >> 3, acg = (t & 7) * 8;   // row 0..63 (+64p), c-col8
    f32x4 acc[4][2] = {};
    f16x8 ha[2], hb[2];
    #pragma unroll
    for (int p = 0; p < 2; ++p) {
        ha[p] = *(const f16x8*)(Ab + (long long)(ar + p * 64) * LC_ + cbeg + acg);
        hb[p] = *(const f16x8*)(Pb + (long long)(ar + p * 64) * LC_ + cbeg + acg);
    }
    for (int c0 = cbeg; c0 < cbeg + G3CHUNK; c0 += 64) {
        #pragma unroll
        for (int p = 0; p < 2; ++p) {
            *(f16x8*)(As + (ar + p * 64) * LDA3 + acg) = ha[p];
            float cmq = colm_s[ar + p * 64];
            f16x8 e;
            if (cmq < -29000.f) {
                #pragma unroll
                for (int j = 0; j < 8; ++j) e[j] = (f16)1.0f;
            } else {
                #pragma unroll
                for (int j = 0; j < 8; ++j)
                    e[j] = (f16)((float)hb[p][j] * __expf(rowm_s[(c0 - cbeg) + acg + j] - cmq));
            }
            *(f16x8*)(Bs + (ar + p * 64) * LDA3 + acg) = e;
        }
        if (c0 + 64 < cbeg + G3CHUNK) {
            #pragma unroll
            for (int p = 0; p < 2; ++p) {
                ha[p] = *(const f16x8*)(Ab + (long long)(ar + p * 64) * LC_ + c0 + 64 + acg);
                hb[p] = *(const f16x8*)(Pb + (long long)(ar + p * 64) * LC_ + c0 + 64 + acg);
            }
        }
        __syncthreads();
        #pragma unroll
        for (int kk = 0; kk < 64; kk += 32) {
            f16x8 af[4], bf[2];
            #pragma unroll
            for (int i = 0; i < 4; ++i)
                af[i] = *(const f16x8*)(As + (wm_off + i * 16 + (lane & 15)) * LDA3 + kk + (lane >> 4) * 8);
            #pragma unroll
            for (int j = 0; j < 2; ++j)
                bf[j] = *(const f16x8*)(Bs + (wn_off + j * 16 + (lane & 15)) * LDA3 + kk + (lane >> 4) * 8);
            #pragma unroll
            for (int i = 0; i < 4; ++i)
                #pragma unroll
                for (int j = 0; j < 2; ++j)
                    acc[i][j] = __builtin_amdgcn_mfma_f32_16x16x32_f16(af[i], bf[j], acc[i][j], 0, 0, 0);
        }
        __syncthreads();
    }
    float* Tb = Tpart + ((long long)split * B_ + b) * (LQ_ * D_);
    #pragma unroll
    for (int i = 0; i < 4; ++i) {
        #pragma unroll
        for (int r = 0; r < 4; ++r) {
            int d = d0 + wm_off + i * 16 + (lane >> 4) * 4 + r;
            float* orow = Tb + (long long)d * LQ_ + q0 + wn_off + (lane & 15);
            #pragma unroll
            for (int j = 0; j < 2; ++j)
                orow[j * 16] = acc[i][j][r];
        }
    }
}

// ---- BN: Bcat[256+d][q] = f16( colinvl[q] * sum_s Tpart[s][b][d][q] ) ----
__global__ __launch_bounds__(256) void k_bnorm(
    const float* __restrict__ Tpart, const float* __restrict__ colinvl,
    f16* __restrict__ Bcat)
{
    const long long i4 = ((long long)blockIdx.x * 256 + threadIdx.x) * 4;
    const int q = (int)(i4 & 255);
    const int d = (int)((i4 >> 8) & 255);
    const int b = (int)(i4 >> 16);
    float4 s = *(const float4*)(Tpart + i4);
    #pragma unroll
    for (int p = 1; p < G3SPLIT; ++p) {
        float4 v = *(const float4*)(Tpart + (long long)p * (B_ * LQ_ * D_) + i4);
        s.x += v.x; s.y += v.y; s.z += v.z; s.w += v.w;
    }
    float4 ci = *(const float4*)(colinvl + b * LQ_ + q);
    f16x4 h;
    h[0] = (f16)(s.x * ci.x); h[1] = (f16)(s.y * ci.y);
    h[2] = (f16)(s.z * ci.z); h[3] = (f16)(s.w * ci.w);
    *(f16x4*)(Bcat + (long long)b * 512 * LQ_ + (long long)(256 + d) * LQ_ + q) = h;
}

// ---- G23: [A | Bmat] = rowinvl * P16 @ Bcat^T ----
// 256c x 256n tiles, 512 threads: p16 re-reads x4->x2, Bcat x16->x8
// (384 -> 256 MB). Flat grid 512 with bijective XCD swizzle.
#define LDA23 40
__global__ __launch_bounds__(512) void k_g23(
    const f16* __restrict__ p16, const float* __restrict__ rowinvl,
    const f16* __restrict__ Bcat,
    float* __restrict__ outA, float* __restrict__ outB)
{
    __shared__ f16 As[256 * LDA23];
    __shared__ f16 Bs[256 * LDA23];
    const int lin = blockIdx.x;
    const int swz = (lin & 7) * 64 + (lin >> 3);
    const int cx = swz & 7;              // c-tile 0..7
    const int ny = (swz >> 3) & 1;       // n-tile 0..1
    const int b  = swz >> 4;             // batch 0..31
    const int c0 = cx * 256, n0 = ny * 256;
    const int t = threadIdx.x, lane = t & 63, wv = t >> 6;   // wv 0..7
    const int wm_off = (wv >> 2) * 128;      // 0 or 128 (c)
    const int wn_off = (wv & 3) * 64;        // 0..192 (n)
    const f16* Ab = p16 + ((long long)b * LC_ + c0) * LQ_;
    const f16* Bb = Bcat + ((long long)b * 512 + n0) * LQ_;
    const int srow = t >> 2, scg = (t & 3) * 8;   // srow 0..127
    f32x4 acc[8][4] = {};
    f16x8 ha[2], hb[2];
    #pragma unroll
    for (int p = 0; p < 2; ++p) {
        int r = srow + p * 128;
        ha[p] = *(const f16x8*)(Ab + (long long)r * LQ_ + scg);
        hb[p] = *(const f16x8*)(Bb + (long long)r * LQ_ + scg);
    }
    for (int k0 = 0; k0 < LQ_; k0 += 32) {
        #pragma unroll
        for (int p = 0; p < 2; ++p) {
            int r = srow + p * 128;
            *(f16x8*)(As + r * LDA23 + scg) = ha[p];
            *(f16x8*)(Bs + r * LDA23 + scg) = hb[p];
        }
        if (k0 + 32 < LQ_) {
            #pragma unroll
            for (int p = 0; p < 2; ++p) {
                int r = srow + p * 128;
                ha[p] = *(const f16x8*)(Ab + (long long)r * LQ_ + k0 + 32 + scg);
                hb[p] = *(const f16x8*)(Bb + (long long)r * LQ_ + k0 + 32 + scg);
            }
        }
        __syncthreads();
        f16x8 bf[4];
        #pragma unroll
        for (int j = 0; j < 4; ++j)
            bf[j] = *(const f16x8*)(Bs + (wn_off + j * 16 + (lane & 15)) * LDA23 + (lane >> 4) * 8);
        #pragma unroll
        for (int i = 0; i < 8; ++i) {
            f16x8 af = *(const f16x8*)(As + (wm_off + i * 16 + (lane & 15)) * LDA23 + (lane >> 4) * 8);
            #pragma unroll
            for (int j = 0; j < 4; ++j)
                acc[i][j] = __builtin_amdgcn_mfma_f32_16x16x32_f16(af, bf[j], acc[i][j], 0, 0, 0);
        }
        __syncthreads();
    }
    float* outp = (n0 == 0) ? outA : outB;
    #pragma unroll
    for (int i = 0; i < 8; ++i) {
        #pragma unroll
        for (int r = 0; r < 4; ++r) {
            int c = c0 + wm_off + i * 16 + (lane >> 4) * 4 + r;
            float ri = rowinvl[b * LC_ + c];
            float* orow = outp + ((long long)b * LC_ + c) * D_ + wn_off + (lane & 15);
            #pragma unroll
            for (int j = 0; j < 4; ++j)
                orow[j * 16] = acc[i][j][r] * ri;
        }
    }
}

extern "C" void kernel_launch(void* const* d_in, const int* in_sizes, int n_in,
                              void* d_out, int out_size, void* d_ws, size_t ws_size,
                              hipStream_t stream) {
    const float* ctx   = (const float*)d_in[0];
    const float* qry   = (const float*)d_in[1];
    const int*   cmask = (const int*)d_in[2];
    const int*   qmask = (const int*)d_in[3];
    const float* w0    = (const float*)d_in[4];
    float* out = (float*)d_out;

    char* w = (char*)d_ws;
    float* sqm     = (float*)w;  w += (long long)8192 * 4;
    float* rowm    = (float*)w;  w += (long long)65536 * 4;
    float* rowinvl = (float*)w;  w += (long long)65536 * 4;
    float* colm    = (float*)w;  w += (long long)8192 * 4;
    float* colinvl = (float*)w;  w += (long long)8192 * 4;
    float* pm      = (float*)w;  w += (long long)524288 * 4;
    float* pl      = (float*)w;  w += (long long)524288 * 4;
    f16*   p16     = (f16*)w;    w += (long long)16777216 * 2;
    f16*   pT16    = (f16*)w;    w += (long long)16777216 * 2;
    f16*   ctxT16  = (f16*)w;    w += (long long)16777216 * 2;
    f16*   qrywm16 = (f16*)w;    w += (long long)2097152 * 2;
    f16*   Bcat    = (f16*)w;    w += (long long)4194304 * 2;
    float* Tpart   = (float*)w;  w += (long long)G3SPLIT * 2097152 * 4;

    k_prepq<<<2048, 256, 0, stream>>>(qry, w0, qmask, qrywm16, sqm);
    k_tq<<<dim3(4, 4, 32), 256, 0, stream>>>(qry, Bcat);
    k_g1<<<dim3(16, 1, 32), 512, 0, stream>>>(ctx, qrywm16, w0, cmask, sqm,
        ctxT16, p16, pT16, rowm, rowinvl, pm, pl);
    k_colreduce<<<32, 256, 0, stream>>>(pm, pl, colm, colinvl);
    k_g3<<<512, 512, 0, stream>>>(ctxT16, pT16, rowm, colm, Tpart);
    k_bnorm<<<2048, 256, 0, stream>>>(Tpart, colinvl, Bcat);
    k_g23<<<512, 512, 0, stream>>>(p16, rowinvl, Bcat,
        out, out + (long long)B_ * LC_ * D_);
}

// Round 7
// 300.058 us; speedup vs baseline: 1.0421x; 1.0320x over previous
//
#include <hip/hip_runtime.h>

#define B_  32
#define LC_ 2048
#define LQ_ 256
#define D_  256
#define NEGH (-30000.0f)   // f16-safe mask value
#define MASKF (-100000.0f) // folded-mask bias: guarantees clamp to NEGH

typedef _Float16 f16;
typedef _Float16 f16x4 __attribute__((ext_vector_type(4)));
typedef _Float16 f16x8 __attribute__((ext_vector_type(8)));
typedef float    f32x4 __attribute__((ext_vector_type(4)));

// ---- P1: fused qry prep: qrywm16 = f16(qry*wm); sqm = qry.wq (mask-folded);
// Bcat[0:256] = f16(qry^T). One pass over qry (was two kernels).
__global__ __launch_bounds__(256) void k_prepq(
    const float* __restrict__ qry, const float* __restrict__ w0,
    const int* __restrict__ qmask,
    f16* __restrict__ qrywm16, float* __restrict__ sqm,
    f16* __restrict__ Bcat)
{
    __shared__ float tile[32 * 260];
    __shared__ float wm_s[256], wq_s[256];
    const int b = blockIdx.y, q0 = blockIdx.x * 32;
    const int t = threadIdx.x;
    wm_s[t] = w0[2 * D_ + t];
    wq_s[t] = w0[D_ + t];
    __syncthreads();
    const int r = t >> 3, s = t & 7;   // r 0..31, s 0..7
    const float* qb = qry + ((long long)(b * LQ_ + q0 + r)) * D_ + s * 32;
    f16* ob = qrywm16 + ((long long)(b * LQ_ + q0 + r)) * D_ + s * 32;
    float dot = 0.f;
    #pragma unroll
    for (int p = 0; p < 8; ++p) {
        float4 v = *(const float4*)(qb + p * 4);
        int cb = s * 32 + p * 4;
        f16x4 h;
        h[0] = (f16)(v.x * wm_s[cb + 0]); h[1] = (f16)(v.y * wm_s[cb + 1]);
        h[2] = (f16)(v.z * wm_s[cb + 2]); h[3] = (f16)(v.w * wm_s[cb + 3]);
        *(f16x4*)(ob + p * 4) = h;
        tile[r * 260 + cb + 0] = v.x;
        tile[r * 260 + cb + 1] = v.y;
        tile[r * 260 + cb + 2] = v.z;
        tile[r * 260 + cb + 3] = v.w;
        dot += v.x * wq_s[cb + 0] + v.y * wq_s[cb + 1]
             + v.z * wq_s[cb + 2] + v.w * wq_s[cb + 3];
    }
    dot += __shfl_xor(dot, 1, 64);
    dot += __shfl_xor(dot, 2, 64);
    dot += __shfl_xor(dot, 4, 64);
    if (s == 0) {
        int q = b * LQ_ + q0 + r;
        sqm[q] = qmask[q] ? MASKF : dot;
    }
    __syncthreads();
    // transpose: thread t = d writes Bcat[d][q0..q0+31] (2-way LDS alias, free)
    {
        f16* orow = Bcat + (long long)b * 512 * LQ_ + (long long)t * LQ_ + q0;
        #pragma unroll
        for (int qq = 0; qq < 32; qq += 4) {
            f16x4 h;
            h[0] = (f16)tile[(qq + 0) * 260 + t];
            h[1] = (f16)tile[(qq + 1) * 260 + t];
            h[2] = (f16)tile[(qq + 2) * 260 + t];
            h[3] = (f16)tile[(qq + 3) * 260 + t];
            *(f16x4*)(orow + qq) = h;
        }
    }
}

// ---- G1: sim = ctx @ qrywm^T + scm + sqm (clamped at NEGH), from fp32 ctx.
// Single-touch ctx: stages fp32->f16, emits ctxT16[d][c] via LDS transpose
// of As (coalesced 16B stores), computes scm inline. No sim16 store: emits
// p16[c][q] = exp(sim-rowm) AND pT16[q][c], plus rowm/rowinvl and pm/pl.
// NOTE: no wave cap — the old (512,4) 128-VGPR cap likely forced scratch
// spills (live set ~140 VGPR); let the allocator pick.
#define LDA1 40
__global__ __launch_bounds__(512) void k_g1(
    const float* __restrict__ ctx, const f16* __restrict__ qrywm16,
    const float* __restrict__ w0, const int* __restrict__ cmask,
    const float* __restrict__ sqm,
    f16* __restrict__ ctxT16, f16* __restrict__ p16, f16* __restrict__ pT16,
    float* __restrict__ rowm, float* __restrict__ rowinvl,
    float* __restrict__ pm, float* __restrict__ pl)
{
    __shared__ f16 As[128 * LDA1];
    __shared__ f16 Bs[256 * LDA1];
    __shared__ float wc_s[256];
    __shared__ float scm_s[128];
    __shared__ float rowpm[4][128], rowps[4][128];
    __shared__ float colpm[2][256], colps[2][256];
    __shared__ float rowmax_s[128], colmax_s[256];
    const int b = blockIdx.z;
    const int c0 = blockIdx.x * 128;
    const int t = threadIdx.x, lane = t & 63, wv = t >> 6;
    const int wm_off = (wv >> 2) * 64, wn_off = (wv & 3) * 64;
    const float* Ab = ctx + ((long long)b * LC_ + c0) * D_;
    const f16* Bb = qrywm16 + (long long)b * LQ_ * D_;
    const int srow = t >> 2, scg = (t & 3) * 8;
    const int td = t & 31, tcc = t >> 5;   // transpose-writer mapping
    if (t < 256) wc_s[t] = w0[t];
    __syncthreads();
    f32x4 acc[4][4] = {};
    float scdot = 0.f;
    for (int k0 = 0; k0 < D_; k0 += 32) {
        float4 a0 = *(const float4*)(Ab + (long long)srow * D_ + k0 + scg);
        float4 a1 = *(const float4*)(Ab + (long long)srow * D_ + k0 + scg + 4);
        f16x8 ha;
        ha[0] = (f16)a0.x; ha[1] = (f16)a0.y; ha[2] = (f16)a0.z; ha[3] = (f16)a0.w;
        ha[4] = (f16)a1.x; ha[5] = (f16)a1.y; ha[6] = (f16)a1.z; ha[7] = (f16)a1.w;
        scdot += a0.x * wc_s[k0 + scg + 0] + a0.y * wc_s[k0 + scg + 1]
               + a0.z * wc_s[k0 + scg + 2] + a0.w * wc_s[k0 + scg + 3]
               + a1.x * wc_s[k0 + scg + 4] + a1.y * wc_s[k0 + scg + 5]
               + a1.z * wc_s[k0 + scg + 6] + a1.w * wc_s[k0 + scg + 7];
        *(f16x8*)(As + srow * LDA1 + scg) = ha;
        *(f16x8*)(Bs + srow * LDA1 + scg) = *(const f16x8*)(Bb + (long long)srow * D_ + k0 + scg);
        *(f16x8*)(Bs + (srow + 128) * LDA1 + scg) = *(const f16x8*)(Bb + (long long)(srow + 128) * D_ + k0 + scg);
        __syncthreads();
        f16x8 af[4], bf[4];
        #pragma unroll
        for (int i = 0; i < 4; ++i)
            af[i] = *(const f16x8*)(As + (wm_off + i * 16 + (lane & 15)) * LDA1 + (lane >> 4) * 8);
        #pragma unroll
        for (int j = 0; j < 4; ++j)
            bf[j] = *(const f16x8*)(Bs + (wn_off + j * 16 + (lane & 15)) * LDA1 + (lane >> 4) * 8);
        #pragma unroll
        for (int i = 0; i < 4; ++i)
            #pragma unroll
            for (int j = 0; j < 4; ++j)
                acc[i][j] = __builtin_amdgcn_mfma_f32_16x16x32_f16(af[i], bf[j], acc[i][j], 0, 0, 0);
        // ctxT16 byproduct: transpose-read As (<=2-way bank alias), coalesced store
        {
            f16x8 hT;
            #pragma unroll
            for (int j = 0; j < 8; ++j)
                hT[j] = As[(tcc * 8 + j) * LDA1 + td];
            *(f16x8*)(ctxT16 + ((long long)b * D_ + k0 + td) * LC_ + c0 + tcc * 8) = hT;
        }
        __syncthreads();
    }
    // finalize scm (mask-folded) into LDS
    scdot += __shfl_xor(scdot, 1, 64);
    scdot += __shfl_xor(scdot, 2, 64);
    if ((t & 3) == 0)
        scm_s[srow] = cmask[b * LC_ + c0 + srow] ? MASKF : scdot;
    __syncthreads();
    // ---- epilogue ----
    float sqv[4];
    #pragma unroll
    for (int j = 0; j < 4; ++j)
        sqv[j] = sqm[b * LQ_ + wn_off + j * 16 + (lane & 15)];
    float scv[4][4];
    #pragma unroll
    for (int i = 0; i < 4; ++i)
        #pragma unroll
        for (int r = 0; r < 4; ++r)
            scv[i][r] = scm_s[wm_off + i * 16 + (lane >> 4) * 4 + r];
    float rmax[4][4], cmax[4];
    #pragma unroll
    for (int i = 0; i < 4; ++i)
        #pragma unroll
        for (int r = 0; r < 4; ++r) rmax[i][r] = -INFINITY;
    #pragma unroll
    for (int j = 0; j < 4; ++j) cmax[j] = -INFINITY;
    // pass 1: track row/col max of f16-rounded values (no sim store)
    #pragma unroll
    for (int i = 0; i < 4; ++i) {
        #pragma unroll
        for (int r = 0; r < 4; ++r) {
            #pragma unroll
            for (int j = 0; j < 4; ++j) {
                float val = fmaxf(acc[i][j][r] + scv[i][r] + sqv[j], NEGH);
                float vr = (float)(f16)val;
                rmax[i][r] = fmaxf(rmax[i][r], vr);
                cmax[j]    = fmaxf(cmax[j], vr);
            }
        }
    }
    #pragma unroll
    for (int i = 0; i < 4; ++i)
        #pragma unroll
        for (int r = 0; r < 4; ++r) {
            rmax[i][r] = fmaxf(rmax[i][r], __shfl_xor(rmax[i][r], 1, 64));
            rmax[i][r] = fmaxf(rmax[i][r], __shfl_xor(rmax[i][r], 2, 64));
            rmax[i][r] = fmaxf(rmax[i][r], __shfl_xor(rmax[i][r], 4, 64));
            rmax[i][r] = fmaxf(rmax[i][r], __shfl_xor(rmax[i][r], 8, 64));
        }
    #pragma unroll
    for (int j = 0; j < 4; ++j) {
        cmax[j] = fmaxf(cmax[j], __shfl_xor(cmax[j], 16, 64));
        cmax[j] = fmaxf(cmax[j], __shfl_xor(cmax[j], 32, 64));
    }
    if ((lane & 15) == 0) {
        #pragma unroll
        for (int i = 0; i < 4; ++i)
            #pragma unroll
            for (int r = 0; r < 4; ++r)
                rowpm[wv & 3][wm_off + i * 16 + (lane >> 4) * 4 + r] = rmax[i][r];
    }
    if (lane < 16) {
        #pragma unroll
        for (int j = 0; j < 4; ++j) colpm[wv >> 2][wn_off + j * 16 + lane] = cmax[j];
    }
    __syncthreads();
    if (t < 128)
        rowmax_s[t] = fmaxf(fmaxf(rowpm[0][t], rowpm[1][t]), fmaxf(rowpm[2][t], rowpm[3][t]));
    if (t < 256)
        colmax_s[t] = fmaxf(colpm[0][t], colpm[1][t]);
    __syncthreads();
    float rmf[4][4], cmf[4];
    #pragma unroll
    for (int i = 0; i < 4; ++i)
        #pragma unroll
        for (int r = 0; r < 4; ++r)
            rmf[i][r] = rowmax_s[wm_off + i * 16 + (lane >> 4) * 4 + r];
    #pragma unroll
    for (int j = 0; j < 4; ++j) cmf[j] = colmax_s[wn_off + j * 16 + (lane & 15)];
    float rsum[4][4] = {}, csum[4] = {};
    // pass 2: sums + store p16[c][q] and pT16[q][c]
    #pragma unroll
    for (int i = 0; i < 4; ++i) {
        #pragma unroll
        for (int r = 0; r < 4; ++r) {
            int c = c0 + wm_off + i * 16 + (lane >> 4) * 4 + r;
            f16* prow = p16 + ((long long)b * LC_ + c) * LQ_ + wn_off + (lane & 15);
            #pragma unroll
            for (int j = 0; j < 4; ++j) {
                int q = wn_off + j * 16 + (lane & 15);
                float val = fmaxf(acc[i][j][r] + scv[i][r] + sqv[j], NEGH);
                float vr = (float)(f16)val;
                float er = __expf(vr - rmf[i][r]);
                f16 hp = (f16)er;
                prow[j * 16] = hp;
                pT16[((long long)b * LQ_ + q) * LC_ + c] = hp;
                rsum[i][r] += er;
                csum[j]    += __expf(vr - cmf[j]);
            }
        }
    }
    #pragma unroll
    for (int i = 0; i < 4; ++i)
        #pragma unroll
        for (int r = 0; r < 4; ++r) {
            rsum[i][r] += __shfl_xor(rsum[i][r], 1, 64);
            rsum[i][r] += __shfl_xor(rsum[i][r], 2, 64);
            rsum[i][r] += __shfl_xor(rsum[i][r], 4, 64);
            rsum[i][r] += __shfl_xor(rsum[i][r], 8, 64);
        }
    #pragma unroll
    for (int j = 0; j < 4; ++j) {
        csum[j] += __shfl_xor(csum[j], 16, 64);
        csum[j] += __shfl_xor(csum[j], 32, 64);
    }
    if ((lane & 15) == 0) {
        #pragma unroll
        for (int i = 0; i < 4; ++i)
            #pragma unroll
            for (int r = 0; r < 4; ++r)
                rowps[wv & 3][wm_off + i * 16 + (lane >> 4) * 4 + r] = rsum[i][r];
    }
    if (lane < 16) {
        #pragma unroll
        for (int j = 0; j < 4; ++j) colps[wv >> 2][wn_off + j * 16 + lane] = csum[j];
    }
    __syncthreads();
    if (t < 128) {
        float l = rowps[0][t] + rowps[1][t] + rowps[2][t] + rowps[3][t];
        rowm[b * LC_ + c0 + t]    = rowmax_s[t];
        rowinvl[b * LC_ + c0 + t] = 1.0f / l;
    }
    if (t < 256) {
        int idx = (b * 16 + blockIdx.x) * LQ_ + t;
        pm[idx] = colmax_s[t];
        pl[idx] = colps[0][t] + colps[1][t];
    }
}

__global__ __launch_bounds__(256) void k_colreduce(
    const float* __restrict__ pm, const float* __restrict__ pl,
    float* __restrict__ colm, float* __restrict__ colinvl)
{
    const int col = blockIdx.x * 256 + threadIdx.x;
    const int b = col >> 8, q = col & 255;
    float M = -INFINITY, L = 0.f;
    for (int ch = 0; ch < 16; ++ch) {
        int idx = (b * 16 + ch) * LQ_ + q;
        float m = pm[idx], l = pl[idx];
        float nM = fmaxf(M, m);
        L = L * __expf(M - nM) + l * __expf(m - nM);
        M = nM;
    }
    colm[col] = M; colinvl[col] = 1.0f / L;
}

// ---- G3: Tpart[s][b][d][q] = sum_c ctxT16[d][c] * (p16[c][q]*exp(rowm[c]-colm[q]))
// 128d x 128q x 512thr; flat grid 512 with bijective XCD swizzle.
#define LDA3 72
#define G3SPLIT 4
#define G3CHUNK (LC_ / G3SPLIT)   // 512
__global__ __launch_bounds__(512) void k_g3(
    const f16* __restrict__ ctxT16, const f16* __restrict__ pT16,
    const float* __restrict__ rowm, const float* __restrict__ colm,
    float* __restrict__ Tpart)
{
    __shared__ f16 As[128 * LDA3];   // [d][c]
    __shared__ f16 Bs[128 * LDA3];   // [q][c]
    __shared__ float rowm_s[G3CHUNK];
    __shared__ float colm_s[128];
    // bijective XCD swizzle: 512 blocks = 8 XCD x 64
    const int lin = blockIdx.x;
    const int swz = (lin & 7) * 64 + (lin >> 3);
    const int combo = swz & 3;             // qt(0..1) + 2*dh(0..1)
    const int split = (swz >> 2) & 3;
    const int b = swz >> 4;
    const int qt = combo & 1, dh = combo >> 1;
    const int q0 = qt * 128, d0 = dh * 128;
    const int cbeg = split * G3CHUNK;
    const int t = threadIdx.x, lane = t & 63, wv = t >> 6;
    const int wm_off = (wv >> 2) * 64, wn_off = (wv & 3) * 32;
    if (t < G3CHUNK) rowm_s[t] = rowm[b * LC_ + cbeg + t];
    if (t < 128) colm_s[t] = colm[b * LQ_ + q0 + t];
    __syncthreads();
    const f16* Ab = ctxT16 + ((long long)b * D_ + d0) * LC_;
    const f16* Pb = pT16 + ((long long)b * LQ_ + q0) * LC_;
    const int ar = t >> 3, acg = (t & 7) * 8;   // row 0..63 (+64p), c-col8
    f32x4 acc[4][2] = {};
    f16x8 ha[2], hb[2];
    #pragma unroll
    for (int p = 0; p < 2; ++p) {
        ha[p] = *(const f16x8*)(Ab + (long long)(ar + p * 64) * LC_ + cbeg + acg);
        hb[p] = *(const f16x8*)(Pb + (long long)(ar + p * 64) * LC_ + cbeg + acg);
    }
    for (int c0 = cbeg; c0 < cbeg + G3CHUNK; c0 += 64) {
        #pragma unroll
        for (int p = 0; p < 2; ++p) {
            *(f16x8*)(As + (ar + p * 64) * LDA3 + acg) = ha[p];
            float cmq = colm_s[ar + p * 64];
            f16x8 e;
            if (cmq < -29000.f) {
                #pragma unroll
                for (int j = 0; j < 8; ++j) e[j] = (f16)1.0f;
            } else {
                #pragma unroll
                for (int j = 0; j < 8; ++j)
                    e[j] = (f16)((float)hb[p][j] * __expf(rowm_s[(c0 - cbeg) + acg + j] - cmq));
            }
            *(f16x8*)(Bs + (ar + p * 64) * LDA3 + acg) = e;
        }
        if (c0 + 64 < cbeg + G3CHUNK) {
            #pragma unroll
            for (int p = 0; p < 2; ++p) {
                ha[p] = *(const f16x8*)(Ab + (long long)(ar + p * 64) * LC_ + c0 + 64 + acg);
                hb[p] = *(const f16x8*)(Pb + (long long)(ar + p * 64) * LC_ + c0 + 64 + acg);
            }
        }
        __syncthreads();
        #pragma unroll
        for (int kk = 0; kk < 64; kk += 32) {
            f16x8 af[4], bf[2];
            #pragma unroll
            for (int i = 0; i < 4; ++i)
                af[i] = *(const f16x8*)(As + (wm_off + i * 16 + (lane & 15)) * LDA3 + kk + (lane >> 4) * 8);
            #pragma unroll
            for (int j = 0; j < 2; ++j)
                bf[j] = *(const f16x8*)(Bs + (wn_off + j * 16 + (lane & 15)) * LDA3 + kk + (lane >> 4) * 8);
            #pragma unroll
            for (int i = 0; i < 4; ++i)
                #pragma unroll
                for (int j = 0; j < 2; ++j)
                    acc[i][j] = __builtin_amdgcn_mfma_f32_16x16x32_f16(af[i], bf[j], acc[i][j], 0, 0, 0);
        }
        __syncthreads();
    }
    float* Tb = Tpart + ((long long)split * B_ + b) * (LQ_ * D_);
    #pragma unroll
    for (int i = 0; i < 4; ++i) {
        #pragma unroll
        for (int r = 0; r < 4; ++r) {
            int d = d0 + wm_off + i * 16 + (lane >> 4) * 4 + r;
            float* orow = Tb + (long long)d * LQ_ + q0 + wn_off + (lane & 15);
            #pragma unroll
            for (int j = 0; j < 2; ++j)
                orow[j * 16] = acc[i][j][r];
        }
    }
}

// ---- BN: Bcat[256+d][q] = f16( colinvl[q] * sum_s Tpart[s][b][d][q] ) ----
__global__ __launch_bounds__(256) void k_bnorm(
    const float* __restrict__ Tpart, const float* __restrict__ colinvl,
    f16* __restrict__ Bcat)
{
    const long long i4 = ((long long)blockIdx.x * 256 + threadIdx.x) * 4;
    const int q = (int)(i4 & 255);
    const int d = (int)((i4 >> 8) & 255);
    const int b = (int)(i4 >> 16);
    float4 s = *(const float4*)(Tpart + i4);
    #pragma unroll
    for (int p = 1; p < G3SPLIT; ++p) {
        float4 v = *(const float4*)(Tpart + (long long)p * (B_ * LQ_ * D_) + i4);
        s.x += v.x; s.y += v.y; s.z += v.z; s.w += v.w;
    }
    float4 ci = *(const float4*)(colinvl + b * LQ_ + q);
    f16x4 h;
    h[0] = (f16)(s.x * ci.x); h[1] = (f16)(s.y * ci.y);
    h[2] = (f16)(s.z * ci.z); h[3] = (f16)(s.w * ci.w);
    *(f16x4*)(Bcat + (long long)b * 512 * LQ_ + (long long)(256 + d) * LQ_ + q) = h;
}

// ---- G23: [A | Bmat] = rowinvl * P16 @ Bcat^T ----
// 256c x 256n tiles, 512 threads; flat grid 512 with bijective XCD swizzle.
#define LDA23 40
__global__ __launch_bounds__(512) void k_g23(
    const f16* __restrict__ p16, const float* __restrict__ rowinvl,
    const f16* __restrict__ Bcat,
    float* __restrict__ outA, float* __restrict__ outB)
{
    __shared__ f16 As[256 * LDA23];
    __shared__ f16 Bs[256 * LDA23];
    const int lin = blockIdx.x;
    const int swz = (lin & 7) * 64 + (lin >> 3);
    const int cx = swz & 7;              // c-tile 0..7
    const int ny = (swz >> 3) & 1;       // n-tile 0..1
    const int b  = swz >> 4;             // batch 0..31
    const int c0 = cx * 256, n0 = ny * 256;
    const int t = threadIdx.x, lane = t & 63, wv = t >> 6;   // wv 0..7
    const int wm_off = (wv >> 2) * 128;      // 0 or 128 (c)
    const int wn_off = (wv & 3) * 64;        // 0..192 (n)
    const f16* Ab = p16 + ((long long)b * LC_ + c0) * LQ_;
    const f16* Bb = Bcat + ((long long)b * 512 + n0) * LQ_;
    const int srow = t >> 2, scg = (t & 3) * 8;   // srow 0..127
    f32x4 acc[8][4] = {};
    f16x8 ha[2], hb[2];
    #pragma unroll
    for (int p = 0; p < 2; ++p) {
        int r = srow + p * 128;
        ha[p] = *(const f16x8*)(Ab + (long long)r * LQ_ + scg);
        hb[p] = *(const f16x8*)(Bb + (long long)r * LQ_ + scg);
    }
    for (int k0 = 0; k0 < LQ_; k0 += 32) {
        #pragma unroll
        for (int p = 0; p < 2; ++p) {
            int r = srow + p * 128;
            *(f16x8*)(As + r * LDA23 + scg) = ha[p];
            *(f16x8*)(Bs + r * LDA23 + scg) = hb[p];
        }
        if (k0 + 32 < LQ_) {
            #pragma unroll
            for (int p = 0; p < 2; ++p) {
                int r = srow + p * 128;
                ha[p] = *(const f16x8*)(Ab + (long long)r * LQ_ + k0 + 32 + scg);
                hb[p] = *(const f16x8*)(Bb + (long long)r * LQ_ + k0 + 32 + scg);
            }
        }
        __syncthreads();
        f16x8 bf[4];
        #pragma unroll
        for (int j = 0; j < 4; ++j)
            bf[j] = *(const f16x8*)(Bs + (wn_off + j * 16 + (lane & 15)) * LDA23 + (lane >> 4) * 8);
        #pragma unroll
        for (int i = 0; i < 8; ++i) {
            f16x8 af = *(const f16x8*)(As + (wm_off + i * 16 + (lane & 15)) * LDA23 + (lane >> 4) * 8);
            #pragma unroll
            for (int j = 0; j < 4; ++j)
                acc[i][j] = __builtin_amdgcn_mfma_f32_16x16x32_f16(af, bf[j], acc[i][j], 0, 0, 0);
        }
        __syncthreads();
    }
    float* outp = (n0 == 0) ? outA : outB;
    #pragma unroll
    for (int i = 0; i < 8; ++i) {
        #pragma unroll
        for (int r = 0; r < 4; ++r) {
            int c = c0 + wm_off + i * 16 + (lane >> 4) * 4 + r;
            float ri = rowinvl[b * LC_ + c];
            float* orow = outp + ((long long)b * LC_ + c) * D_ + wn_off + (lane & 15);
            #pragma unroll
            for (int j = 0; j < 4; ++j)
                orow[j * 16] = acc[i][j][r] * ri;
        }
    }
}

extern "C" void kernel_launch(void* const* d_in, const int* in_sizes, int n_in,
                              void* d_out, int out_size, void* d_ws, size_t ws_size,
                              hipStream_t stream) {
    const float* ctx   = (const float*)d_in[0];
    const float* qry   = (const float*)d_in[1];
    const int*   cmask = (const int*)d_in[2];
    const int*   qmask = (const int*)d_in[3];
    const float* w0    = (const float*)d_in[4];
    float* out = (float*)d_out;

    char* w = (char*)d_ws;
    float* sqm     = (float*)w;  w += (long long)8192 * 4;
    float* rowm    = (float*)w;  w += (long long)65536 * 4;
    float* rowinvl = (float*)w;  w += (long long)65536 * 4;
    float* colm    = (float*)w;  w += (long long)8192 * 4;
    float* colinvl = (float*)w;  w += (long long)8192 * 4;
    float* pm      = (float*)w;  w += (long long)524288 * 4;
    float* pl      = (float*)w;  w += (long long)524288 * 4;
    f16*   p16     = (f16*)w;    w += (long long)16777216 * 2;
    f16*   pT16    = (f16*)w;    w += (long long)16777216 * 2;
    f16*   ctxT16  = (f16*)w;    w += (long long)16777216 * 2;
    f16*   qrywm16 = (f16*)w;    w += (long long)2097152 * 2;
    f16*   Bcat    = (f16*)w;    w += (long long)4194304 * 2;
    float* Tpart   = (float*)w;  w += (long long)G3SPLIT * 2097152 * 4;

    k_prepq<<<dim3(8, 32), 256, 0, stream>>>(qry, w0, qmask, qrywm16, sqm, Bcat);
    k_g1<<<dim3(16, 1, 32), 512, 0, stream>>>(ctx, qrywm16, w0, cmask, sqm,
        ctxT16, p16, pT16, rowm, rowinvl, pm, pl);
    k_colreduce<<<32, 256, 0, stream>>>(pm, pl, colm, colinvl);
    k_g3<<<512, 512, 0, stream>>>(ctxT16, pT16, rowm, colm, Tpart);
    k_bnorm<<<2048, 256, 0, stream>>>(Tpart, colinvl, Bcat);
    k_g23<<<512, 512, 0, stream>>>(p16, rowinvl, Bcat,
        out, out + (long long)B_ * LC_ * D_);
}